// Round 18
// baseline (427.715 us; speedup 1.0000x reference)
//
#include <hip/hip_runtime.h>

typedef unsigned short u16;
typedef unsigned int   u32;

#define NB     512
#define NHEADS 8
#define HW     361
#define NPIX   184832      /* NB*HW */
#define NTOT   768
#define EPSBN  1e-5f
#define RS     0.17677669529663687f   /* sqrt(32)/32 */

typedef __bf16 bf16x8 __attribute__((ext_vector_type(8)));
typedef float  f32x4  __attribute__((ext_vector_type(4)));

__device__ __forceinline__ u16 f2bf(float f) {
  u32 u = __float_as_uint(f);
  u += 0x7fffu + ((u >> 16) & 1u);          // round-to-nearest-even
  return (u16)(u >> 16);
}
__device__ __forceinline__ float bf2f(u16 v) {
  return __uint_as_float(((u32)v) << 16);
}
__device__ __forceinline__ bf16x8 ldb8(const void* p) {
  return __builtin_bit_cast(bf16x8, *(const uint4*)p);
}
__device__ __forceinline__ float dot2(u32 a, u32 b) {
  return bf2f((u16)a) * bf2f((u16)b) + bf2f((u16)(a >> 16)) * bf2f((u16)(b >> 16));
}
__device__ __forceinline__ float dot8(uint4 a, uint4 b) {
  return dot2(a.x, b.x) + dot2(a.y, b.y) + dot2(a.z, b.z) + dot2(a.w, b.w);
}

// ---------------- kernel 0: W -> bf16 [768][256]; bias; zero sx
__global__ __launch_bounds__(256) void k_prep(
    const float* __restrict__ Wq, const float* __restrict__ bq,
    const float* __restrict__ Wk, const float* __restrict__ bk,
    const float* __restrict__ Wv, const float* __restrict__ bv,
    u16* __restrict__ Wall, float* __restrict__ ball,
    float* __restrict__ sx) {
  const int n = blockIdx.x, t = threadIdx.x;
  const float* src; const float* bs; int r;
  if (n < 256)      { src = Wq; bs = bq; r = n; }
  else if (n < 512) { src = Wk; bs = bk; r = n - 256; }
  else              { src = Wv; bs = bv; r = n - 512; }
  Wall[n * 256 + t] = f2bf(src[r * 256 + t]);
  if (t == 0) ball[n] = bs[r];
  if (n == 0) sx[t] = 0.f;
}

// ---------------- kernel 1: M partials + sx + fused xT write
// grid 512 = (image-pair g, c1-half); wave owns 16-row c1 strip (acc[16] = 64 AGPR)
// -> 2 blocks/CU co-resident; pair-halves adjacent on one XCD (L2-shared x reads)
__global__ __launch_bounds__(512) void k_M(
    const float* __restrict__ x, u16* __restrict__ xT,
    float* __restrict__ Mpart, float* __restrict__ sx) {
  __shared__ u16 Als[256 * 64];                    // 32 KB
  const int tid  = threadIdx.x;
  const int orig = blockIdx.x;                     // 0..511
  const int xcd  = orig & 7, kk8 = orig >> 3;      // consecutive k -> same XCD
  const int g    = xcd * 32 + (kk8 >> 1);          // image pair 0..255
  const int half = kk8 & 1;                        // c1 half 0/1
  const int lane = tid & 63, w = tid >> 6;         // 8 waves
  const int l15 = lane & 15, kq = lane >> 4;
  const int sc  = tid >> 4;                        // staging c low (0..31)
  const int sq  = tid & 15;                        // staging px quad
  const int wpx = tid & 63;                        // xT-write px in chunk
  const int wcs = tid >> 6;                        // xT-write c-slice (*32)
  char* Ab = (char*)Als;
  const int c1base = half * 128 + w * 16;          // this wave's c1 strip

  float sxp[8];
  f32x4 acc[16];
  #pragma unroll
  for (int i = 0; i < 8; ++i) sxp[i] = 0.f;
  #pragma unroll
  for (int f2 = 0; f2 < 16; ++f2) acc[f2] = (f32x4){0.f, 0.f, 0.f, 0.f};

  #pragma unroll 1
  for (int ch = 0; ch < 12; ++ch) {
    const int img = (ch >= 6) ? 1 : 0;
    const int px0 = (ch - img * 6) * 64;
    const int bb  = g * 2 + img;
    const int pb  = px0 + sq * 4;
    // stage: 2 batches of 4 float4 loads (caps live regs at 16)
    #pragma unroll
    for (int b4 = 0; b4 < 2; ++b4) {
      float4 fv[4];
      #pragma unroll
      for (int i2 = 0; i2 < 4; ++i2) {
        const int c = sc + 32 * (b4 * 4 + i2);
        const float* xp = x + ((size_t)bb * 256 + c) * HW + pb;
        if (pb + 3 < HW) {
          fv[i2] = *(const float4*)xp;
        } else {
          fv[i2].x = (pb + 0 < HW) ? xp[0] : 0.f;
          fv[i2].y = (pb + 1 < HW) ? xp[1] : 0.f;
          fv[i2].z = (pb + 2 < HW) ? xp[2] : 0.f;
          fv[i2].w = (pb + 3 < HW) ? xp[3] : 0.f;
        }
      }
      #pragma unroll
      for (int i2 = 0; i2 < 4; ++i2) {
        const int i = b4 * 4 + i2;
        const int c = sc + 32 * i;
        sxp[i] += fv[i2].x + fv[i2].y + fv[i2].z + fv[i2].w;
        const u32 lo = (u32)f2bf(fv[i2].x) | ((u32)f2bf(fv[i2].y) << 16);
        const u32 hi = (u32)f2bf(fv[i2].z) | ((u32)f2bf(fv[i2].w) << 16);
        const int slot = (sq >> 1) ^ (c & 7);      // XOR swizzle
        *(uint2*)(Ab + c * 128 + slot * 16 + (sq & 1) * 8) = make_uint2(lo, hi);
      }
    }
    __syncthreads();
    // MFMA: K=64 (2 steps); wave strip c1base..+16, all 256 c2
    #pragma unroll
    for (int kk = 0; kk < 2; ++kk) {
      const int gl = kk * 4 + kq;
      const int so = ((gl ^ (l15 & 7)) << 4);
      const bf16x8 a = ldb8(Ab + (c1base + l15) * 128 + so);
      #pragma unroll
      for (int f2 = 0; f2 < 16; ++f2) {
        const bf16x8 b = ldb8(Ab + (f2 * 16 + l15) * 128 + so);
        acc[f2] = __builtin_amdgcn_mfma_f32_16x16x32_bf16(a, b, acc[f2], 0, 0, 0);
      }
    }
    // fused xT write (only half 0 blocks)
    if (half == 0) {
      const int pxg = px0 + wpx;
      if (pxg < HW) {
        __align__(16) u16 tmp[32];
        #pragma unroll
        for (int j = 0; j < 32; ++j) {
          const int c = wcs * 32 + j;
          tmp[j] = Als[c * 64 + (((wpx >> 3) ^ (c & 7)) << 3) + (wpx & 7)];
        }
        uint4* dst = (uint4*)(xT + ((size_t)bb * HW + pxg) * 256 + wcs * 32);
        dst[0] = ((const uint4*)tmp)[0];
        dst[1] = ((const uint4*)tmp)[1];
        dst[2] = ((const uint4*)tmp)[2];
        dst[3] = ((const uint4*)tmp)[3];
      }
    }
    __syncthreads();
  }
  // store M partials (disjoint rows per half -> no race)
  float* mp = Mpart + (size_t)g * 65536;
  #pragma unroll
  for (int f2 = 0; f2 < 16; ++f2)
    #pragma unroll
    for (int j = 0; j < 4; ++j) {
      const int c1 = c1base + kq * 4 + j;
      mp[c1 * 256 + f2 * 16 + l15] = acc[f2][j];
    }
  if (half == 0) {
    #pragma unroll
    for (int i = 0; i < 8; ++i) {
      float v = sxp[i];
      v += __shfl_down(v, 8); v += __shfl_down(v, 4);
      v += __shfl_down(v, 2); v += __shfl_down(v, 1);
      if (sq == 0) atomicAdd(&sx[sc + 32 * i], v);
    }
  }
}

// ---------------- kernel 1c: reduce 256 partials -> Mg (deterministic)
__global__ __launch_bounds__(256) void k_red(const float* __restrict__ Mpart,
                                             float* __restrict__ Mg) {
  const int i = blockIdx.x * 256 + threadIdx.x;
  float s = 0.f;
  #pragma unroll 8
  for (int sl = 0; sl < 256; ++sl) s += Mpart[(size_t)sl * 65536 + i];
  Mg[i] = s;
}

// ---------------- kernel 2: finalize BN via moments: s_all, t_all
__global__ __launch_bounds__(256) void k_stats2(
    const float* __restrict__ Mg, const float* __restrict__ sx,
    const float* __restrict__ Wq, const float* __restrict__ bq,
    const float* __restrict__ Wk, const float* __restrict__ bk,
    const float* __restrict__ Wv, const float* __restrict__ bv,
    const float* __restrict__ gQ, const float* __restrict__ betaQ,
    const float* __restrict__ gK, const float* __restrict__ betaK,
    const float* __restrict__ gV, const float* __restrict__ betaV,
    float* __restrict__ s_all, float* __restrict__ t_all) {
  __shared__ float ws[256];
  __shared__ float r1[4], r2[4];
  const int n = blockIdx.x, i = threadIdx.x;
  const int which = n >> 8, r = n & 255;
  const float* src = (which == 0) ? Wq : (which == 1) ? Wk : Wv;
  const float wi = src[r * 256 + i];
  ws[i] = wi;
  __syncthreads();
  float colsum = 0.f;
  #pragma unroll 4
  for (int j = 0; j < 256; ++j) colsum += Mg[j * 256 + i] * ws[j];
  float p1 = wi * sx[i];
  float p2 = wi * colsum;
  p1 += __shfl_down(p1, 32); p2 += __shfl_down(p2, 32);
  p1 += __shfl_down(p1, 16); p2 += __shfl_down(p2, 16);
  p1 += __shfl_down(p1, 8);  p2 += __shfl_down(p2, 8);
  p1 += __shfl_down(p1, 4);  p2 += __shfl_down(p2, 4);
  p1 += __shfl_down(p1, 2);  p2 += __shfl_down(p2, 2);
  p1 += __shfl_down(p1, 1);  p2 += __shfl_down(p2, 1);
  const int wv = i >> 6;
  if ((i & 63) == 0) { r1[wv] = p1; r2[wv] = p2; }
  __syncthreads();
  if (i == 0) {
    const float S1 = r1[0] + r1[1] + r1[2] + r1[3];
    const float S2 = r2[0] + r2[1] + r2[2] + r2[3];
    const float* bs = (which == 0) ? bq : (which == 1) ? bk : bv;
    const float* gs = (which == 0) ? gQ : (which == 1) ? gK : gV;
    const float* be = (which == 0) ? betaQ : (which == 1) ? betaK : betaV;
    const float b = bs[r];
    const float P = (float)NPIX;
    const float mean = (S1 + P * b) / P;
    const float Ey2  = (S2 + 2.f * b * S1 + P * b * b) / P;
    const float var  = Ey2 - mean * mean;
    const float s    = gs[r] * rsqrtf(var + EPSBN);
    s_all[n] = s;
    t_all[n] = be[r] - s * mean;
  }
}

// ---------------- kernel 3: fused QKV-GEMM + neighbor attention (R16, known-good)
__global__ __launch_bounds__(768) void k_fused(
    const u16* __restrict__ xT, const u16* __restrict__ Wall,
    const float* __restrict__ ball,
    const float* __restrict__ s_all, const float* __restrict__ t_all,
    const float* __restrict__ x, float* __restrict__ out) {
  __shared__ u16   Wl[96 * 256];                   // 48 KB, XOR-swizzled rows
  __shared__ __align__(16) u16 P[HW * 104];        // 75,088 B: [px][Q|K|V]
  __shared__ float aL[4 * HW];
  __shared__ float stl[2 * 96];
  const int tid = threadIdx.x;
  const int wg  = blockIdx.x;                      // 0..2047
  const int xcd = wg & 7, ii = wg >> 3;
  const int h   = ii & 7;
  const int pr  = xcd * 32 + (ii >> 3);
  const int bb0 = pr * 2;
  const char* Pb = (const char*)P;

  const int lane = tid & 63, wv = tid >> 6;
  const int l15 = lane & 15, kq = lane >> 4;

  const bool pact = tid < 2 * HW;
  const int  ppx  = pact ? ((tid < HW) ? tid : tid - HW) : 0;
  const int  poc0 = (tid < HW) ? 0 : 16;

  uint4 bfr[16];
  {
    const u16* xTb = xT + (size_t)bb0 * HW * 256;
    #pragma unroll
    for (int ks = 0; ks < 8; ++ks) {
      bfr[2 * ks]     = *(const uint4*)(xTb + (size_t)(wv * 32      + l15) * 256 + ks * 32 + kq * 8);
      bfr[2 * ks + 1] = *(const uint4*)(xTb + (size_t)(wv * 32 + 16 + l15) * 256 + ks * 32 + kq * 8);
    }
  }
  float xres[16];
  if (pact) {
    const size_t pg = ((size_t)bb0 * 256 + h * 32 + poc0) * HW + ppx;
    #pragma unroll
    for (int o = 0; o < 16; ++o) xres[o] = x[pg + (size_t)o * HW];
  }
  if (tid < 96) {
    const int which = tid >> 5, c32 = tid & 31;
    const int n = which * 256 + h * 32 + c32;
    float s = s_all[n];
    float t = s * ball[n] + t_all[n];
    if (tid < 32) { s *= RS; t *= RS; }
    stl[tid] = s; stl[96 + tid] = t;
  }
  #pragma unroll
  for (int i = 0; i < 4; ++i) {
    const int gi = tid + i * 768;
    const int lr = gi >> 5, gg = gi & 31;
    const int which = lr >> 5, c32 = lr & 31;
    uint4 v = *(const uint4*)(Wall + (size_t)(which * 256 + h * 32 + c32) * 256 + gg * 8);
    const int slot = gg ^ (lr & 7);
    *(uint4*)((char*)Wl + lr * 512 + slot * 16) = v;
  }
  __syncthreads();

  #pragma unroll
  for (int im = 0; im < 2; ++im) {
    const int bb = bb0 + im;
    f32x4 acc[6][2];
    #pragma unroll
    for (int f = 0; f < 6; ++f) {
      acc[f][0] = (f32x4){0.f, 0.f, 0.f, 0.f};
      acc[f][1] = (f32x4){0.f, 0.f, 0.f, 0.f};
    }
    #pragma unroll
    for (int ks = 0; ks < 8; ++ks) {
      bf16x8 b0 = __builtin_bit_cast(bf16x8, bfr[2 * ks]);
      bf16x8 b1 = __builtin_bit_cast(bf16x8, bfr[2 * ks + 1]);
      const int slot = ((ks * 4 + kq) ^ (l15 & 7)) * 16;
      #pragma unroll
      for (int f = 0; f < 6; ++f) {
        const int lr = (f >> 1) * 32 + (f & 1) * 16 + l15;
        bf16x8 a = ldb8((const char*)Wl + lr * 512 + slot);
        acc[f][0] = __builtin_amdgcn_mfma_f32_16x16x32_bf16(a, b0, acc[f][0], 0, 0, 0);
        acc[f][1] = __builtin_amdgcn_mfma_f32_16x16x32_bf16(a, b1, acc[f][1], 0, 0, 0);
      }
    }
    if (im == 0) {
      const u16* xTb2 = xT + (size_t)(bb0 + 1) * HW * 256;
      #pragma unroll
      for (int ks = 0; ks < 8; ++ks) {
        bfr[2 * ks]     = *(const uint4*)(xTb2 + (size_t)(wv * 32      + l15) * 256 + ks * 32 + kq * 8);
        bfr[2 * ks + 1] = *(const uint4*)(xTb2 + (size_t)(wv * 32 + 16 + l15) * 256 + ks * 32 + kq * 8);
      }
    }
    #pragma unroll
    for (int f = 0; f < 6; ++f) {
      const int ch0 = f * 16 + kq * 4;
      const float s0 = stl[ch0],     t0 = stl[96 + ch0];
      const float s1 = stl[ch0 + 1], t1 = stl[96 + ch0 + 1];
      const float s2 = stl[ch0 + 2], t2 = stl[96 + ch0 + 2];
      const float s3 = stl[ch0 + 3], t3 = stl[96 + ch0 + 3];
      #pragma unroll
      for (int p2 = 0; p2 < 2; ++p2) {
        const int px = wv * 32 + p2 * 16 + l15;
        if (px < HW) {
          const u32 lo = (u32)f2bf(s0 * acc[f][p2][0] + t0)
                       | ((u32)f2bf(s1 * acc[f][p2][1] + t1) << 16);
          const u32 hi = (u32)f2bf(s2 * acc[f][p2][2] + t2)
                       | ((u32)f2bf(s3 * acc[f][p2][3] + t3) << 16);
          *(uint2*)((char*)P + px * 208 + f * 32 + kq * 8) = make_uint2(lo, hi);
        }
      }
    }
    __syncthreads();

    if (tid < HW) {
      const int px = tid;
      const int yy = px / 19, xx = px - yy * 19;
      const bool i0 = yy > 0, i1 = yy < 18, i2 = xx > 0, i3 = xx < 18;
      const int pn0 = i0 ? px - 19 : px, pn1 = i1 ? px + 19 : px;
      const int pn2 = i2 ? px - 1  : px, pn3 = i3 ? px + 1  : px;
      const uint4* Qp = (const uint4*)(Pb + px * 208);
      const uint4 q0 = Qp[0], q1 = Qp[1], q2 = Qp[2], q3 = Qp[3];
      const uint4* K0 = (const uint4*)(Pb + pn0 * 208 + 64);
      const uint4* K1 = (const uint4*)(Pb + pn1 * 208 + 64);
      const uint4* K2 = (const uint4*)(Pb + pn2 * 208 + 64);
      const uint4* K3 = (const uint4*)(Pb + pn3 * 208 + 64);
      float l0 = dot8(q0, K0[0]) + dot8(q1, K0[1]) + dot8(q2, K0[2]) + dot8(q3, K0[3]);
      float l1 = dot8(q0, K1[0]) + dot8(q1, K1[1]) + dot8(q2, K1[2]) + dot8(q3, K1[3]);
      float l2 = dot8(q0, K2[0]) + dot8(q1, K2[1]) + dot8(q2, K2[2]) + dot8(q3, K2[3]);
      float l3 = dot8(q0, K3[0]) + dot8(q1, K3[1]) + dot8(q2, K3[2]) + dot8(q3, K3[3]);
      l0 = i0 ? l0 : 0.f; l1 = i1 ? l1 : 0.f;
      l2 = i2 ? l2 : 0.f; l3 = i3 ? l3 : 0.f;
      const float mx = fmaxf(fmaxf(l0, l1), fmaxf(l2, l3));
      const float e0 = __expf(l0 - mx), e1 = __expf(l1 - mx);
      const float e2 = __expf(l2 - mx), e3 = __expf(l3 - mx);
      const float inv = 1.f / (e0 + e1 + e2 + e3);
      aL[0 * HW + px] = i0 ? e0 * inv : 0.f;
      aL[1 * HW + px] = i1 ? e1 * inv : 0.f;
      aL[2 * HW + px] = i2 ? e2 * inv : 0.f;
      aL[3 * HW + px] = i3 ? e3 * inv : 0.f;
    }
    __syncthreads();

    if (pact) {
      const int px = ppx;
      const size_t pgb = ((size_t)bb * 256 + h * 32 + poc0) * HW + px;
      const int yy = px / 19, xx = px - yy * 19;
      const int pn0 = (yy > 0)  ? px - 19 : px, pn1 = (yy < 18) ? px + 19 : px;
      const int pn2 = (xx > 0)  ? px - 1  : px, pn3 = (xx < 18) ? px + 1  : px;
      const float a0 = aL[0 * HW + px], a1 = aL[1 * HW + px];
      const float a2 = aL[2 * HW + px], a3 = aL[3 * HW + px];
      const int vb = 128 + poc0 * 2;
      const uint4* V0 = (const uint4*)(Pb + pn0 * 208 + vb);
      const uint4* V1 = (const uint4*)(Pb + pn1 * 208 + vb);
      const uint4* V2 = (const uint4*)(Pb + pn2 * 208 + vb);
      const uint4* V3 = (const uint4*)(Pb + pn3 * 208 + vb);
      #pragma unroll
      for (int half = 0; half < 2; ++half) {
        const uint4 w0 = V0[half], w1 = V1[half], w2 = V2[half], w3 = V3[half];
        const u32 u0[4] = {w0.x, w0.y, w0.z, w0.w};
        const u32 u1[4] = {w1.x, w1.y, w1.z, w1.w};
        const u32 u2[4] = {w2.x, w2.y, w2.z, w2.w};
        const u32 u3[4] = {w3.x, w3.y, w3.z, w3.w};
        #pragma unroll
        for (int p = 0; p < 4; ++p) {
          const int o = half * 8 + p * 2;
          float vlo = a0 * bf2f((u16)u0[p]) + a1 * bf2f((u16)u1[p])
                    + a2 * bf2f((u16)u2[p]) + a3 * bf2f((u16)u3[p]);
          float vhi = a0 * bf2f((u16)(u0[p] >> 16)) + a1 * bf2f((u16)(u1[p] >> 16))
                    + a2 * bf2f((u16)(u2[p] >> 16)) + a3 * bf2f((u16)(u3[p] >> 16));
          vlo = fmaxf(vlo, 0.f);
          vhi = fmaxf(vhi, 0.f);
          out[pgb + (size_t)o * HW]       = vlo + xres[o];
          out[pgb + (size_t)(o + 1) * HW] = vhi + xres[o + 1];
        }
      }
    }
    if (im == 0 && pact) {
      const size_t pg2 = ((size_t)(bb0 + 1) * 256 + h * 32 + poc0) * HW + ppx;
      #pragma unroll
      for (int o = 0; o < 16; ++o) xres[o] = x[pg2 + (size_t)o * HW];
    }
    __syncthreads();
  }
}

// ---------------- workspace layout
constexpr size_t OFF_XT    = 0;
constexpr size_t SZ_XT     = (size_t)NPIX * 512 + 16384;
constexpr size_t OFF_WALL  = OFF_XT + SZ_XT;
constexpr size_t SZ_WALL   = (size_t)NTOT * 512;
constexpr size_t OFF_BALL  = OFF_WALL + SZ_WALL;
constexpr size_t OFF_M     = OFF_BALL + NTOT * 4;
constexpr size_t SZ_M      = 256 * 256 * 4;
constexpr size_t OFF_SX    = OFF_M + SZ_M;
constexpr size_t OFF_SALL  = OFF_SX + 256 * 4;
constexpr size_t OFF_TALL  = OFF_SALL + NTOT * 4;
constexpr size_t OFF_MPART = OFF_TALL + NTOT * 4;
constexpr size_t SZ_MPART  = (size_t)256 * 65536 * 4;   // 67 MB
constexpr size_t WS_NEEDED = OFF_MPART + SZ_MPART;

extern "C" void kernel_launch(void* const* d_in, const int* in_sizes, int n_in,
                              void* d_out, int out_size, void* d_ws, size_t ws_size,
                              hipStream_t stream) {
  (void)in_sizes; (void)n_in; (void)out_size;
  if (ws_size < WS_NEEDED) return;

  const float* x     = (const float*)d_in[0];
  const float* Wq    = (const float*)d_in[1];
  const float* bq    = (const float*)d_in[2];
  const float* Wk    = (const float*)d_in[3];
  const float* bk    = (const float*)d_in[4];
  const float* Wv    = (const float*)d_in[5];
  const float* bv    = (const float*)d_in[6];
  const float* gQ    = (const float*)d_in[7];
  const float* betaQ = (const float*)d_in[8];
  const float* gK    = (const float*)d_in[9];
  const float* betaK = (const float*)d_in[10];
  const float* gV    = (const float*)d_in[11];
  const float* betaV = (const float*)d_in[12];
  float* out = (float*)d_out;

  char* wsp = (char*)d_ws;
  u16*   xT    = (u16*)(wsp + OFF_XT);
  u16*   Wall  = (u16*)(wsp + OFF_WALL);
  float* ball  = (float*)(wsp + OFF_BALL);
  float* Mg    = (float*)(wsp + OFF_M);
  float* sx    = (float*)(wsp + OFF_SX);
  float* s_all = (float*)(wsp + OFF_SALL);
  float* t_all = (float*)(wsp + OFF_TALL);
  float* Mpart = (float*)(wsp + OFF_MPART);

  k_prep<<<NTOT, 256, 0, stream>>>(Wq, bq, Wk, bk, Wv, bv, Wall, ball, sx);
  k_M<<<512, 512, 0, stream>>>(x, xT, Mpart, sx);
  k_red<<<256, 256, 0, stream>>>(Mpart, Mg);
  k_stats2<<<NTOT, 256, 0, stream>>>(Mg, sx, Wq, bq, Wk, bk, Wv, bv,
                                     gQ, betaQ, gK, betaK, gV, betaV, s_all, t_all);
  k_fused<<<2048, 768, 0, stream>>>(xT, Wall, ball, s_all, t_all, x, out);
}

// Round 19
// 419.488 us; speedup vs baseline: 1.0196x; 1.0196x over previous
//
#include <hip/hip_runtime.h>

typedef unsigned short u16;
typedef unsigned int   u32;

#define NB     512
#define NHEADS 8
#define HW     361
#define NPIX   184832      /* NB*HW */
#define NTOT   768
#define EPSBN  1e-5f
#define RS     0.17677669529663687f   /* sqrt(32)/32 */

typedef __bf16 bf16x8 __attribute__((ext_vector_type(8)));
typedef float  f32x4  __attribute__((ext_vector_type(4)));

__device__ __forceinline__ u16 f2bf(float f) {
  u32 u = __float_as_uint(f);
  u += 0x7fffu + ((u >> 16) & 1u);          // round-to-nearest-even
  return (u16)(u >> 16);
}
__device__ __forceinline__ float bf2f(u16 v) {
  return __uint_as_float(((u32)v) << 16);
}
__device__ __forceinline__ bf16x8 ldb8(const void* p) {
  return __builtin_bit_cast(bf16x8, *(const uint4*)p);
}
__device__ __forceinline__ float dot2(u32 a, u32 b) {
  return bf2f((u16)a) * bf2f((u16)b) + bf2f((u16)(a >> 16)) * bf2f((u16)(b >> 16));
}
__device__ __forceinline__ float dot8(uint4 a, uint4 b) {
  return dot2(a.x, b.x) + dot2(a.y, b.y) + dot2(a.z, b.z) + dot2(a.w, b.w);
}

// ---------------- kernel 0: W -> bf16 [768][256]; bias; zero sx
__global__ __launch_bounds__(256) void k_prep(
    const float* __restrict__ Wq, const float* __restrict__ bq,
    const float* __restrict__ Wk, const float* __restrict__ bk,
    const float* __restrict__ Wv, const float* __restrict__ bv,
    u16* __restrict__ Wall, float* __restrict__ ball,
    float* __restrict__ sx) {
  const int n = blockIdx.x, t = threadIdx.x;
  const float* src; const float* bs; int r;
  if (n < 256)      { src = Wq; bs = bq; r = n; }
  else if (n < 512) { src = Wk; bs = bk; r = n - 256; }
  else              { src = Wv; bs = bv; r = n - 512; }
  Wall[n * 256 + t] = f2bf(src[r * 256 + t]);
  if (t == 0) ball[n] = bs[r];
  if (n == 0) sx[t] = 0.f;
}

// ---------------- kernel 1: M partials + sx + fused xT write (x read ONCE)
// 256 blocks (2 images) x 512 thr; acc[2][16]; swizzle (c^(c>>3))&7;
// xT write COALESCED: lanes 0-31 emit one contiguous 512B px-row
__global__ __launch_bounds__(512) void k_M(
    const float* __restrict__ x, u16* __restrict__ xT,
    float* __restrict__ Mpart, float* __restrict__ sx) {
  __shared__ u16 Als[256 * 64];                    // 32 KB
  const int tid = threadIdx.x, g = blockIdx.x;     // images 2g, 2g+1
  const int lane = tid & 63, w = tid >> 6;         // 8 waves
  const int l15 = lane & 15, kq = lane >> 4;
  const int sc  = tid >> 4;                        // staging c low (0..31)
  const int sq  = tid & 15;                        // staging px quad
  const int col16 = tid & 31;                      // xT-write column (x8 ch)
  const int pxw   = tid >> 5;                      // xT-write px base (0..15)
  char* Ab = (char*)Als;

  float sxp[8];
  f32x4 acc[2][16];
  #pragma unroll
  for (int i = 0; i < 8; ++i) sxp[i] = 0.f;
  #pragma unroll
  for (int f2 = 0; f2 < 16; ++f2) {
    acc[0][f2] = (f32x4){0.f, 0.f, 0.f, 0.f};
    acc[1][f2] = (f32x4){0.f, 0.f, 0.f, 0.f};
  }

  #pragma unroll 1
  for (int ch = 0; ch < 12; ++ch) {
    const int img = (ch >= 6) ? 1 : 0;
    const int px0 = (ch - img * 6) * 64;
    const int bb  = g * 2 + img;
    const int pb  = px0 + sq * 4;
    // stage: 8 float4 loads/thread, [c][px] direct
    #pragma unroll
    for (int i = 0; i < 8; ++i) {
      const int c = sc + 32 * i;
      const float* xp = x + ((size_t)bb * 256 + c) * HW + pb;
      float v0, v1, v2, v3;
      if (pb + 3 < HW) {
        const float4 f4 = *(const float4*)xp;
        v0 = f4.x; v1 = f4.y; v2 = f4.z; v3 = f4.w;
      } else {
        v0 = (pb + 0 < HW) ? xp[0] : 0.f;
        v1 = (pb + 1 < HW) ? xp[1] : 0.f;
        v2 = (pb + 2 < HW) ? xp[2] : 0.f;
        v3 = (pb + 3 < HW) ? xp[3] : 0.f;
      }
      sxp[i] += v0 + v1 + v2 + v3;
      const u32 lo = (u32)f2bf(v0) | ((u32)f2bf(v1) << 16);
      const u32 hi = (u32)f2bf(v2) | ((u32)f2bf(v3) << 16);
      const int slot = (sq >> 1) ^ ((c ^ (c >> 3)) & 7);
      *(uint2*)(Ab + c * 128 + slot * 16 + (sq & 1) * 8) = make_uint2(lo, hi);
    }
    __syncthreads();
    // MFMA: K=64 (2 steps); wave w owns c1 strip [32w, 32w+32), all 256 c2
    #pragma unroll
    for (int kk = 0; kk < 2; ++kk) {
      const int gl = kk * 4 + kq;
      const int r0 = w * 32 + l15;
      const int r1 = r0 + 16;
      const bf16x8 a0 = ldb8(Ab + r0 * 128 + ((gl ^ ((r0 ^ (r0 >> 3)) & 7)) << 4));
      const bf16x8 a1 = ldb8(Ab + r1 * 128 + ((gl ^ ((r1 ^ (r1 >> 3)) & 7)) << 4));
      #pragma unroll
      for (int f2 = 0; f2 < 16; ++f2) {
        const int rb = f2 * 16 + l15;
        const bf16x8 b = ldb8(Ab + rb * 128 + ((gl ^ ((rb ^ (rb >> 3)) & 7)) << 4));
        acc[0][f2] = __builtin_amdgcn_mfma_f32_16x16x32_bf16(a0, b, acc[0][f2], 0, 0, 0);
        acc[1][f2] = __builtin_amdgcn_mfma_f32_16x16x32_bf16(a1, b, acc[1][f2], 0, 0, 0);
      }
    }
    // fused xT write, COALESCED: item (j): px = j*16+pxw, cols col16*8..+8
    #pragma unroll
    for (int j = 0; j < 4; ++j) {
      const int pxl = j * 16 + pxw;
      const int pxg = px0 + pxl;
      if (pxg < HW) {
        __align__(16) u16 tmp[8];
        #pragma unroll
        for (int jj = 0; jj < 8; ++jj) {
          const int c = col16 * 8 + jj;
          const int slot = (pxl >> 3) ^ ((c ^ (c >> 3)) & 7);
          tmp[jj] = Als[c * 64 + slot * 8 + (pxl & 7)];
        }
        *(uint4*)(xT + ((size_t)bb * HW + pxg) * 256 + col16 * 8) = *(const uint4*)tmp;
      }
    }
    __syncthreads();
  }
  // store M partials (plain coalesced, no atomics)
  float* mp = Mpart + (size_t)g * 65536;
  #pragma unroll
  for (int f1 = 0; f1 < 2; ++f1)
    #pragma unroll
    for (int f2 = 0; f2 < 16; ++f2)
      #pragma unroll
      for (int j = 0; j < 4; ++j) {
        const int c1 = w * 32 + f1 * 16 + kq * 4 + j;
        const int c2 = f2 * 16 + l15;
        mp[c1 * 256 + c2] = acc[f1][f2][j];
      }
  #pragma unroll
  for (int i = 0; i < 8; ++i) {
    float v = sxp[i];
    v += __shfl_down(v, 8); v += __shfl_down(v, 4);
    v += __shfl_down(v, 2); v += __shfl_down(v, 1);
    if (sq == 0) atomicAdd(&sx[sc + 32 * i], v);
  }
}

// ---------------- kernel 1c: reduce 256 partials -> Mg (deterministic)
__global__ __launch_bounds__(256) void k_red(const float* __restrict__ Mpart,
                                             float* __restrict__ Mg) {
  const int i = blockIdx.x * 256 + threadIdx.x;
  float s = 0.f;
  #pragma unroll 8
  for (int sl = 0; sl < 256; ++sl) s += Mpart[(size_t)sl * 65536 + i];
  Mg[i] = s;
}

// ---------------- kernel 2: finalize BN via moments: s_all, t_all
__global__ __launch_bounds__(256) void k_stats2(
    const float* __restrict__ Mg, const float* __restrict__ sx,
    const float* __restrict__ Wq, const float* __restrict__ bq,
    const float* __restrict__ Wk, const float* __restrict__ bk,
    const float* __restrict__ Wv, const float* __restrict__ bv,
    const float* __restrict__ gQ, const float* __restrict__ betaQ,
    const float* __restrict__ gK, const float* __restrict__ betaK,
    const float* __restrict__ gV, const float* __restrict__ betaV,
    float* __restrict__ s_all, float* __restrict__ t_all) {
  __shared__ float ws[256];
  __shared__ float r1[4], r2[4];
  const int n = blockIdx.x, i = threadIdx.x;
  const int which = n >> 8, r = n & 255;
  const float* src = (which == 0) ? Wq : (which == 1) ? Wk : Wv;
  const float wi = src[r * 256 + i];
  ws[i] = wi;
  __syncthreads();
  float colsum = 0.f;
  #pragma unroll 4
  for (int j = 0; j < 256; ++j) colsum += Mg[j * 256 + i] * ws[j];
  float p1 = wi * sx[i];
  float p2 = wi * colsum;
  p1 += __shfl_down(p1, 32); p2 += __shfl_down(p2, 32);
  p1 += __shfl_down(p1, 16); p2 += __shfl_down(p2, 16);
  p1 += __shfl_down(p1, 8);  p2 += __shfl_down(p2, 8);
  p1 += __shfl_down(p1, 4);  p2 += __shfl_down(p2, 4);
  p1 += __shfl_down(p1, 2);  p2 += __shfl_down(p2, 2);
  p1 += __shfl_down(p1, 1);  p2 += __shfl_down(p2, 1);
  const int wv = i >> 6;
  if ((i & 63) == 0) { r1[wv] = p1; r2[wv] = p2; }
  __syncthreads();
  if (i == 0) {
    const float S1 = r1[0] + r1[1] + r1[2] + r1[3];
    const float S2 = r2[0] + r2[1] + r2[2] + r2[3];
    const float* bs = (which == 0) ? bq : (which == 1) ? bk : bv;
    const float* gs = (which == 0) ? gQ : (which == 1) ? gK : gV;
    const float* be = (which == 0) ? betaQ : (which == 1) ? betaK : betaV;
    const float b = bs[r];
    const float P = (float)NPIX;
    const float mean = (S1 + P * b) / P;
    const float Ey2  = (S2 + 2.f * b * S1 + P * b * b) / P;
    const float var  = Ey2 - mean * mean;
    const float s    = gs[r] * rsqrtf(var + EPSBN);
    s_all[n] = s;
    t_all[n] = be[r] - s * mean;
  }
}

// ---------------- kernel 3: fused QKV-GEMM + neighbor attention (R16, known-good)
__global__ __launch_bounds__(768) void k_fused(
    const u16* __restrict__ xT, const u16* __restrict__ Wall,
    const float* __restrict__ ball,
    const float* __restrict__ s_all, const float* __restrict__ t_all,
    const float* __restrict__ x, float* __restrict__ out) {
  __shared__ u16   Wl[96 * 256];                   // 48 KB, XOR-swizzled rows
  __shared__ __align__(16) u16 P[HW * 104];        // 75,088 B: [px][Q|K|V]
  __shared__ float aL[4 * HW];
  __shared__ float stl[2 * 96];
  const int tid = threadIdx.x;
  const int wg  = blockIdx.x;                      // 0..2047
  const int xcd = wg & 7, ii = wg >> 3;
  const int h   = ii & 7;
  const int pr  = xcd * 32 + (ii >> 3);
  const int bb0 = pr * 2;
  const char* Pb = (const char*)P;

  const int lane = tid & 63, wv = tid >> 6;
  const int l15 = lane & 15, kq = lane >> 4;

  const bool pact = tid < 2 * HW;
  const int  ppx  = pact ? ((tid < HW) ? tid : tid - HW) : 0;
  const int  poc0 = (tid < HW) ? 0 : 16;

  uint4 bfr[16];
  {
    const u16* xTb = xT + (size_t)bb0 * HW * 256;
    #pragma unroll
    for (int ks = 0; ks < 8; ++ks) {
      bfr[2 * ks]     = *(const uint4*)(xTb + (size_t)(wv * 32      + l15) * 256 + ks * 32 + kq * 8);
      bfr[2 * ks + 1] = *(const uint4*)(xTb + (size_t)(wv * 32 + 16 + l15) * 256 + ks * 32 + kq * 8);
    }
  }
  float xres[16];
  if (pact) {
    const size_t pg = ((size_t)bb0 * 256 + h * 32 + poc0) * HW + ppx;
    #pragma unroll
    for (int o = 0; o < 16; ++o) xres[o] = x[pg + (size_t)o * HW];
  }
  if (tid < 96) {
    const int which = tid >> 5, c32 = tid & 31;
    const int n = which * 256 + h * 32 + c32;
    float s = s_all[n];
    float t = s * ball[n] + t_all[n];
    if (tid < 32) { s *= RS; t *= RS; }
    stl[tid] = s; stl[96 + tid] = t;
  }
  #pragma unroll
  for (int i = 0; i < 4; ++i) {
    const int gi = tid + i * 768;
    const int lr = gi >> 5, gg = gi & 31;
    const int which = lr >> 5, c32 = lr & 31;
    uint4 v = *(const uint4*)(Wall + (size_t)(which * 256 + h * 32 + c32) * 256 + gg * 8);
    const int slot = gg ^ (lr & 7);
    *(uint4*)((char*)Wl + lr * 512 + slot * 16) = v;
  }
  __syncthreads();

  #pragma unroll
  for (int im = 0; im < 2; ++im) {
    const int bb = bb0 + im;
    f32x4 acc[6][2];
    #pragma unroll
    for (int f = 0; f < 6; ++f) {
      acc[f][0] = (f32x4){0.f, 0.f, 0.f, 0.f};
      acc[f][1] = (f32x4){0.f, 0.f, 0.f, 0.f};
    }
    #pragma unroll
    for (int ks = 0; ks < 8; ++ks) {
      bf16x8 b0 = __builtin_bit_cast(bf16x8, bfr[2 * ks]);
      bf16x8 b1 = __builtin_bit_cast(bf16x8, bfr[2 * ks + 1]);
      const int slot = ((ks * 4 + kq) ^ (l15 & 7)) * 16;
      #pragma unroll
      for (int f = 0; f < 6; ++f) {
        const int lr = (f >> 1) * 32 + (f & 1) * 16 + l15;
        bf16x8 a = ldb8((const char*)Wl + lr * 512 + slot);
        acc[f][0] = __builtin_amdgcn_mfma_f32_16x16x32_bf16(a, b0, acc[f][0], 0, 0, 0);
        acc[f][1] = __builtin_amdgcn_mfma_f32_16x16x32_bf16(a, b1, acc[f][1], 0, 0, 0);
      }
    }
    if (im == 0) {
      const u16* xTb2 = xT + (size_t)(bb0 + 1) * HW * 256;
      #pragma unroll
      for (int ks = 0; ks < 8; ++ks) {
        bfr[2 * ks]     = *(const uint4*)(xTb2 + (size_t)(wv * 32      + l15) * 256 + ks * 32 + kq * 8);
        bfr[2 * ks + 1] = *(const uint4*)(xTb2 + (size_t)(wv * 32 + 16 + l15) * 256 + ks * 32 + kq * 8);
      }
    }
    #pragma unroll
    for (int f = 0; f < 6; ++f) {
      const int ch0 = f * 16 + kq * 4;
      const float s0 = stl[ch0],     t0 = stl[96 + ch0];
      const float s1 = stl[ch0 + 1], t1 = stl[96 + ch0 + 1];
      const float s2 = stl[ch0 + 2], t2 = stl[96 + ch0 + 2];
      const float s3 = stl[ch0 + 3], t3 = stl[96 + ch0 + 3];
      #pragma unroll
      for (int p2 = 0; p2 < 2; ++p2) {
        const int px = wv * 32 + p2 * 16 + l15;
        if (px < HW) {
          const u32 lo = (u32)f2bf(s0 * acc[f][p2][0] + t0)
                       | ((u32)f2bf(s1 * acc[f][p2][1] + t1) << 16);
          const u32 hi = (u32)f2bf(s2 * acc[f][p2][2] + t2)
                       | ((u32)f2bf(s3 * acc[f][p2][3] + t3) << 16);
          *(uint2*)((char*)P + px * 208 + f * 32 + kq * 8) = make_uint2(lo, hi);
        }
      }
    }
    __syncthreads();

    if (tid < HW) {
      const int px = tid;
      const int yy = px / 19, xx = px - yy * 19;
      const bool i0 = yy > 0, i1 = yy < 18, i2 = xx > 0, i3 = xx < 18;
      const int pn0 = i0 ? px - 19 : px, pn1 = i1 ? px + 19 : px;
      const int pn2 = i2 ? px - 1  : px, pn3 = i3 ? px + 1  : px;
      const uint4* Qp = (const uint4*)(Pb + px * 208);
      const uint4 q0 = Qp[0], q1 = Qp[1], q2 = Qp[2], q3 = Qp[3];
      const uint4* K0 = (const uint4*)(Pb + pn0 * 208 + 64);
      const uint4* K1 = (const uint4*)(Pb + pn1 * 208 + 64);
      const uint4* K2 = (const uint4*)(Pb + pn2 * 208 + 64);
      const uint4* K3 = (const uint4*)(Pb + pn3 * 208 + 64);
      float l0 = dot8(q0, K0[0]) + dot8(q1, K0[1]) + dot8(q2, K0[2]) + dot8(q3, K0[3]);
      float l1 = dot8(q0, K1[0]) + dot8(q1, K1[1]) + dot8(q2, K1[2]) + dot8(q3, K1[3]);
      float l2 = dot8(q0, K2[0]) + dot8(q1, K2[1]) + dot8(q2, K2[2]) + dot8(q3, K2[3]);
      float l3 = dot8(q0, K3[0]) + dot8(q1, K3[1]) + dot8(q2, K3[2]) + dot8(q3, K3[3]);
      l0 = i0 ? l0 : 0.f; l1 = i1 ? l1 : 0.f;
      l2 = i2 ? l2 : 0.f; l3 = i3 ? l3 : 0.f;
      const float mx = fmaxf(fmaxf(l0, l1), fmaxf(l2, l3));
      const float e0 = __expf(l0 - mx), e1 = __expf(l1 - mx);
      const float e2 = __expf(l2 - mx), e3 = __expf(l3 - mx);
      const float inv = 1.f / (e0 + e1 + e2 + e3);
      aL[0 * HW + px] = i0 ? e0 * inv : 0.f;
      aL[1 * HW + px] = i1 ? e1 * inv : 0.f;
      aL[2 * HW + px] = i2 ? e2 * inv : 0.f;
      aL[3 * HW + px] = i3 ? e3 * inv : 0.f;
    }
    __syncthreads();

    if (pact) {
      const int px = ppx;
      const size_t pgb = ((size_t)bb * 256 + h * 32 + poc0) * HW + px;
      const int yy = px / 19, xx = px - yy * 19;
      const int pn0 = (yy > 0)  ? px - 19 : px, pn1 = (yy < 18) ? px + 19 : px;
      const int pn2 = (xx > 0)  ? px - 1  : px, pn3 = (xx < 18) ? px + 1  : px;
      const float a0 = aL[0 * HW + px], a1 = aL[1 * HW + px];
      const float a2 = aL[2 * HW + px], a3 = aL[3 * HW + px];
      const int vb = 128 + poc0 * 2;
      const uint4* V0 = (const uint4*)(Pb + pn0 * 208 + vb);
      const uint4* V1 = (const uint4*)(Pb + pn1 * 208 + vb);
      const uint4* V2 = (const uint4*)(Pb + pn2 * 208 + vb);
      const uint4* V3 = (const uint4*)(Pb + pn3 * 208 + vb);
      #pragma unroll
      for (int half = 0; half < 2; ++half) {
        const uint4 w0 = V0[half], w1 = V1[half], w2 = V2[half], w3 = V3[half];
        const u32 u0[4] = {w0.x, w0.y, w0.z, w0.w};
        const u32 u1[4] = {w1.x, w1.y, w1.z, w1.w};
        const u32 u2[4] = {w2.x, w2.y, w2.z, w2.w};
        const u32 u3[4] = {w3.x, w3.y, w3.z, w3.w};
        #pragma unroll
        for (int p = 0; p < 4; ++p) {
          const int o = half * 8 + p * 2;
          float vlo = a0 * bf2f((u16)u0[p]) + a1 * bf2f((u16)u1[p])
                    + a2 * bf2f((u16)u2[p]) + a3 * bf2f((u16)u3[p]);
          float vhi = a0 * bf2f((u16)(u0[p] >> 16)) + a1 * bf2f((u16)(u1[p] >> 16))
                    + a2 * bf2f((u16)(u2[p] >> 16)) + a3 * bf2f((u16)(u3[p] >> 16));
          vlo = fmaxf(vlo, 0.f);
          vhi = fmaxf(vhi, 0.f);
          out[pgb + (size_t)o * HW]       = vlo + xres[o];
          out[pgb + (size_t)(o + 1) * HW] = vhi + xres[o + 1];
        }
      }
    }
    if (im == 0 && pact) {
      const size_t pg2 = ((size_t)(bb0 + 1) * 256 + h * 32 + poc0) * HW + ppx;
      #pragma unroll
      for (int o = 0; o < 16; ++o) xres[o] = x[pg2 + (size_t)o * HW];
    }
    __syncthreads();
  }
}

// ---------------- workspace layout
constexpr size_t OFF_XT    = 0;
constexpr size_t SZ_XT     = (size_t)NPIX * 512 + 16384;
constexpr size_t OFF_WALL  = OFF_XT + SZ_XT;
constexpr size_t SZ_WALL   = (size_t)NTOT * 512;
constexpr size_t OFF_BALL  = OFF_WALL + SZ_WALL;
constexpr size_t OFF_M     = OFF_BALL + NTOT * 4;
constexpr size_t SZ_M      = 256 * 256 * 4;
constexpr size_t OFF_SX    = OFF_M + SZ_M;
constexpr size_t OFF_SALL  = OFF_SX + 256 * 4;
constexpr size_t OFF_TALL  = OFF_SALL + NTOT * 4;
constexpr size_t OFF_MPART = OFF_TALL + NTOT * 4;
constexpr size_t SZ_MPART  = (size_t)256 * 65536 * 4;   // 67 MB
constexpr size_t WS_NEEDED = OFF_MPART + SZ_MPART;

extern "C" void kernel_launch(void* const* d_in, const int* in_sizes, int n_in,
                              void* d_out, int out_size, void* d_ws, size_t ws_size,
                              hipStream_t stream) {
  (void)in_sizes; (void)n_in; (void)out_size;
  if (ws_size < WS_NEEDED) return;

  const float* x     = (const float*)d_in[0];
  const float* Wq    = (const float*)d_in[1];
  const float* bq    = (const float*)d_in[2];
  const float* Wk    = (const float*)d_in[3];
  const float* bk    = (const float*)d_in[4];
  const float* Wv    = (const float*)d_in[5];
  const float* bv    = (const float*)d_in[6];
  const float* gQ    = (const float*)d_in[7];
  const float* betaQ = (const float*)d_in[8];
  const float* gK    = (const float*)d_in[9];
  const float* betaK = (const float*)d_in[10];
  const float* gV    = (const float*)d_in[11];
  const float* betaV = (const float*)d_in[12];
  float* out = (float*)d_out;

  char* wsp = (char*)d_ws;
  u16*   xT    = (u16*)(wsp + OFF_XT);
  u16*   Wall  = (u16*)(wsp + OFF_WALL);
  float* ball  = (float*)(wsp + OFF_BALL);
  float* Mg    = (float*)(wsp + OFF_M);
  float* sx    = (float*)(wsp + OFF_SX);
  float* s_all = (float*)(wsp + OFF_SALL);
  float* t_all = (float*)(wsp + OFF_TALL);
  float* Mpart = (float*)(wsp + OFF_MPART);

  k_prep<<<NTOT, 256, 0, stream>>>(Wq, bq, Wk, bk, Wv, bv, Wall, ball, sx);
  k_M<<<256, 512, 0, stream>>>(x, xT, Mpart, sx);
  k_red<<<256, 256, 0, stream>>>(Mpart, Mg);
  k_stats2<<<NTOT, 256, 0, stream>>>(Mg, sx, Wq, bq, Wk, bk, Wv, bv,
                                     gQ, betaQ, gK, betaK, gV, betaV, s_all, t_all);
  k_fused<<<2048, 768, 0, stream>>>(xT, Wall, ball, s_all, t_all, x, out);
}

// Round 20
// 374.428 us; speedup vs baseline: 1.1423x; 1.1203x over previous
//
#include <hip/hip_runtime.h>

typedef unsigned short u16;
typedef unsigned int   u32;

#define NB     512
#define NHEADS 8
#define HW     361
#define NPIX   184832      /* NB*HW */
#define NTOT   768
#define EPSBN  1e-5f
#define RS     0.17677669529663687f   /* sqrt(32)/32 */

typedef __bf16 bf16x8 __attribute__((ext_vector_type(8)));
typedef float  f32x4  __attribute__((ext_vector_type(4)));

__device__ __forceinline__ u16 f2bf(float f) {
  u32 u = __float_as_uint(f);
  u += 0x7fffu + ((u >> 16) & 1u);          // round-to-nearest-even
  return (u16)(u >> 16);
}
__device__ __forceinline__ float bf2f(u16 v) {
  return __uint_as_float(((u32)v) << 16);
}
__device__ __forceinline__ bf16x8 ldb8(const void* p) {
  return __builtin_bit_cast(bf16x8, *(const uint4*)p);
}
__device__ __forceinline__ float dot2(u32 a, u32 b) {
  return bf2f((u16)a) * bf2f((u16)b) + bf2f((u16)(a >> 16)) * bf2f((u16)(b >> 16));
}
__device__ __forceinline__ float dot8(uint4 a, uint4 b) {
  return dot2(a.x, b.x) + dot2(a.y, b.y) + dot2(a.z, b.z) + dot2(a.w, b.w);
}

// ---------------- kernel 0: W -> bf16 [768][256]; bias; zero sx
__global__ __launch_bounds__(256) void k_prep(
    const float* __restrict__ Wq, const float* __restrict__ bq,
    const float* __restrict__ Wk, const float* __restrict__ bk,
    const float* __restrict__ Wv, const float* __restrict__ bv,
    u16* __restrict__ Wall, float* __restrict__ ball,
    float* __restrict__ sx) {
  const int n = blockIdx.x, t = threadIdx.x;
  const float* src; const float* bs; int r;
  if (n < 256)      { src = Wq; bs = bq; r = n; }
  else if (n < 512) { src = Wk; bs = bk; r = n - 256; }
  else              { src = Wv; bs = bv; r = n - 512; }
  Wall[n * 256 + t] = f2bf(src[r * 256 + t]);
  if (t == 0) ball[n] = bs[r];
  if (n == 0) sx[t] = 0.f;
}

// ---------------- kernel 1: M partials + sx + fused xT write (x read ONCE)
// R16 version (known-good): 256 blocks (2 images) x 512 thr; acc[2][16]
__global__ __launch_bounds__(512) void k_M(
    const float* __restrict__ x, u16* __restrict__ xT,
    float* __restrict__ Mpart, float* __restrict__ sx) {
  __shared__ u16 Als[256 * 64];                    // 32 KB
  const int tid = threadIdx.x, g = blockIdx.x;     // images 2g, 2g+1
  const int lane = tid & 63, w = tid >> 6;         // 8 waves
  const int l15 = lane & 15, kq = lane >> 4;
  const int sc  = tid >> 4;                        // staging c low (0..31)
  const int sq  = tid & 15;                        // staging px quad
  const int wpx = tid & 63;                        // xT-write px in chunk
  const int wcs = tid >> 6;                        // xT-write c-slice (*32)
  char* Ab = (char*)Als;

  float sxp[8];
  f32x4 acc[2][16];
  #pragma unroll
  for (int i = 0; i < 8; ++i) sxp[i] = 0.f;
  #pragma unroll
  for (int f2 = 0; f2 < 16; ++f2) {
    acc[0][f2] = (f32x4){0.f, 0.f, 0.f, 0.f};
    acc[1][f2] = (f32x4){0.f, 0.f, 0.f, 0.f};
  }

  #pragma unroll 1
  for (int ch = 0; ch < 12; ++ch) {
    const int img = (ch >= 6) ? 1 : 0;
    const int px0 = (ch - img * 6) * 64;
    const int bb  = g * 2 + img;
    const int pb  = px0 + sq * 4;
    #pragma unroll
    for (int i = 0; i < 8; ++i) {
      const int c = sc + 32 * i;
      const float* xp = x + ((size_t)bb * 256 + c) * HW + pb;
      float v0, v1, v2, v3;
      if (pb + 3 < HW) {
        const float4 f4 = *(const float4*)xp;
        v0 = f4.x; v1 = f4.y; v2 = f4.z; v3 = f4.w;
      } else {
        v0 = (pb + 0 < HW) ? xp[0] : 0.f;
        v1 = (pb + 1 < HW) ? xp[1] : 0.f;
        v2 = (pb + 2 < HW) ? xp[2] : 0.f;
        v3 = (pb + 3 < HW) ? xp[3] : 0.f;
      }
      sxp[i] += v0 + v1 + v2 + v3;
      const u32 lo = (u32)f2bf(v0) | ((u32)f2bf(v1) << 16);
      const u32 hi = (u32)f2bf(v2) | ((u32)f2bf(v3) << 16);
      const int slot = (sq >> 1) ^ (c & 7);        // XOR swizzle
      *(uint2*)(Ab + c * 128 + slot * 16 + (sq & 1) * 8) = make_uint2(lo, hi);
    }
    __syncthreads();
    #pragma unroll
    for (int kk = 0; kk < 2; ++kk) {
      const int gl = kk * 4 + kq;
      const int so = ((gl ^ (l15 & 7)) << 4);
      const int r0 = w * 32 + l15;
      const bf16x8 a0 = ldb8(Ab + r0 * 128 + so);
      const bf16x8 a1 = ldb8(Ab + (r0 + 16) * 128 + so);
      #pragma unroll
      for (int f2 = 0; f2 < 16; ++f2) {
        const bf16x8 b = ldb8(Ab + (f2 * 16 + l15) * 128 + so);
        acc[0][f2] = __builtin_amdgcn_mfma_f32_16x16x32_bf16(a0, b, acc[0][f2], 0, 0, 0);
        acc[1][f2] = __builtin_amdgcn_mfma_f32_16x16x32_bf16(a1, b, acc[1][f2], 0, 0, 0);
      }
    }
    const int pxg = px0 + wpx;
    if (pxg < HW) {
      __align__(16) u16 tmp[32];
      #pragma unroll
      for (int j = 0; j < 32; ++j) {
        const int c = wcs * 32 + j;
        tmp[j] = Als[c * 64 + (((wpx >> 3) ^ (c & 7)) << 3) + (wpx & 7)];
      }
      uint4* dst = (uint4*)(xT + ((size_t)bb * HW + pxg) * 256 + wcs * 32);
      dst[0] = ((const uint4*)tmp)[0];
      dst[1] = ((const uint4*)tmp)[1];
      dst[2] = ((const uint4*)tmp)[2];
      dst[3] = ((const uint4*)tmp)[3];
    }
    __syncthreads();
  }
  float* mp = Mpart + (size_t)g * 65536;
  #pragma unroll
  for (int f1 = 0; f1 < 2; ++f1)
    #pragma unroll
    for (int f2 = 0; f2 < 16; ++f2)
      #pragma unroll
      for (int j = 0; j < 4; ++j) {
        const int c1 = w * 32 + f1 * 16 + kq * 4 + j;
        const int c2 = f2 * 16 + l15;
        mp[c1 * 256 + c2] = acc[f1][f2][j];
      }
  #pragma unroll
  for (int i = 0; i < 8; ++i) {
    float v = sxp[i];
    v += __shfl_down(v, 8); v += __shfl_down(v, 4);
    v += __shfl_down(v, 2); v += __shfl_down(v, 1);
    if (sq == 0) atomicAdd(&sx[sc + 32 * i], v);
  }
}

// ---------------- kernel 1c: reduce 256 partials -> Mg (deterministic)
__global__ __launch_bounds__(256) void k_red(const float* __restrict__ Mpart,
                                             float* __restrict__ Mg) {
  const int i = blockIdx.x * 256 + threadIdx.x;
  float s = 0.f;
  #pragma unroll 8
  for (int sl = 0; sl < 256; ++sl) s += Mpart[(size_t)sl * 65536 + i];
  Mg[i] = s;
}

// ---------------- kernel 2: finalize BN via moments: s_all, t_all
__global__ __launch_bounds__(256) void k_stats2(
    const float* __restrict__ Mg, const float* __restrict__ sx,
    const float* __restrict__ Wq, const float* __restrict__ bq,
    const float* __restrict__ Wk, const float* __restrict__ bk,
    const float* __restrict__ Wv, const float* __restrict__ bv,
    const float* __restrict__ gQ, const float* __restrict__ betaQ,
    const float* __restrict__ gK, const float* __restrict__ betaK,
    const float* __restrict__ gV, const float* __restrict__ betaV,
    float* __restrict__ s_all, float* __restrict__ t_all) {
  __shared__ float ws[256];
  __shared__ float r1[4], r2[4];
  const int n = blockIdx.x, i = threadIdx.x;
  const int which = n >> 8, r = n & 255;
  const float* src = (which == 0) ? Wq : (which == 1) ? Wk : Wv;
  const float wi = src[r * 256 + i];
  ws[i] = wi;
  __syncthreads();
  float colsum = 0.f;
  #pragma unroll 4
  for (int j = 0; j < 256; ++j) colsum += Mg[j * 256 + i] * ws[j];
  float p1 = wi * sx[i];
  float p2 = wi * colsum;
  p1 += __shfl_down(p1, 32); p2 += __shfl_down(p2, 32);
  p1 += __shfl_down(p1, 16); p2 += __shfl_down(p2, 16);
  p1 += __shfl_down(p1, 8);  p2 += __shfl_down(p2, 8);
  p1 += __shfl_down(p1, 4);  p2 += __shfl_down(p2, 4);
  p1 += __shfl_down(p1, 2);  p2 += __shfl_down(p2, 2);
  p1 += __shfl_down(p1, 1);  p2 += __shfl_down(p2, 1);
  const int wv = i >> 6;
  if ((i & 63) == 0) { r1[wv] = p1; r2[wv] = p2; }
  __syncthreads();
  if (i == 0) {
    const float S1 = r1[0] + r1[1] + r1[2] + r1[3];
    const float S2 = r2[0] + r2[1] + r2[2] + r2[3];
    const float* bs = (which == 0) ? bq : (which == 1) ? bk : bv;
    const float* gs = (which == 0) ? gQ : (which == 1) ? gK : gV;
    const float* be = (which == 0) ? betaQ : (which == 1) ? betaK : betaV;
    const float b = bs[r];
    const float P = (float)NPIX;
    const float mean = (S1 + P * b) / P;
    const float Ey2  = (S2 + 2.f * b * S1 + P * b * b) / P;
    const float var  = Ey2 - mean * mean;
    const float s    = gs[r] * rsqrtf(var + EPSBN);
    s_all[n] = s;
    t_all[n] = be[r] - s * mean;
  }
}

// ---------------- kernel 3: fused QKV-GEMM + neighbor attention
// R16 structure; residual now read from bf16 xT (2 uint4 loads vs 16 f32)
__global__ __launch_bounds__(768) void k_fused(
    const u16* __restrict__ xT, const u16* __restrict__ Wall,
    const float* __restrict__ ball,
    const float* __restrict__ s_all, const float* __restrict__ t_all,
    float* __restrict__ out) {
  __shared__ u16   Wl[96 * 256];                   // 48 KB, XOR-swizzled rows
  __shared__ __align__(16) u16 P[HW * 104];        // 75,088 B: [px][Q|K|V]
  __shared__ float aL[4 * HW];
  __shared__ float stl[2 * 96];
  const int tid = threadIdx.x;
  const int wg  = blockIdx.x;                      // 0..2047
  const int xcd = wg & 7, ii = wg >> 3;
  const int h   = ii & 7;
  const int pr  = xcd * 32 + (ii >> 3);
  const int bb0 = pr * 2;
  const char* Pb = (const char*)P;

  const int lane = tid & 63, wv = tid >> 6;
  const int l15 = lane & 15, kq = lane >> 4;

  const bool pact = tid < 2 * HW;
  const int  ppx  = pact ? ((tid < HW) ? tid : tid - HW) : 0;
  const int  poc0 = (tid < HW) ? 0 : 16;

  uint4 bfr[16];
  {
    const u16* xTb = xT + (size_t)bb0 * HW * 256;
    #pragma unroll
    for (int ks = 0; ks < 8; ++ks) {
      bfr[2 * ks]     = *(const uint4*)(xTb + (size_t)(wv * 32      + l15) * 256 + ks * 32 + kq * 8);
      bfr[2 * ks + 1] = *(const uint4*)(xTb + (size_t)(wv * 32 + 16 + l15) * 256 + ks * 32 + kq * 8);
    }
  }
  // residual prefetch from bf16 xT (channels h*32+poc0 .. +16, contiguous)
  float xres[16];
  if (pact) {
    const uint4* xr = (const uint4*)(xT + ((size_t)bb0 * HW + ppx) * 256 + h * 32 + poc0);
    const uint4 r0 = xr[0], r1 = xr[1];
    const u32 uu[8] = {r0.x, r0.y, r0.z, r0.w, r1.x, r1.y, r1.z, r1.w};
    #pragma unroll
    for (int p = 0; p < 8; ++p) {
      xres[2 * p]     = bf2f((u16)uu[p]);
      xres[2 * p + 1] = bf2f((u16)(uu[p] >> 16));
    }
  }
  if (tid < 96) {
    const int which = tid >> 5, c32 = tid & 31;
    const int n = which * 256 + h * 32 + c32;
    float s = s_all[n];
    float t = s * ball[n] + t_all[n];
    if (tid < 32) { s *= RS; t *= RS; }
    stl[tid] = s; stl[96 + tid] = t;
  }
  #pragma unroll
  for (int i = 0; i < 4; ++i) {
    const int gi = tid + i * 768;
    const int lr = gi >> 5, gg = gi & 31;
    const int which = lr >> 5, c32 = lr & 31;
    uint4 v = *(const uint4*)(Wall + (size_t)(which * 256 + h * 32 + c32) * 256 + gg * 8);
    const int slot = gg ^ (lr & 7);
    *(uint4*)((char*)Wl + lr * 512 + slot * 16) = v;
  }
  __syncthreads();

  #pragma unroll
  for (int im = 0; im < 2; ++im) {
    const int bb = bb0 + im;
    f32x4 acc[6][2];
    #pragma unroll
    for (int f = 0; f < 6; ++f) {
      acc[f][0] = (f32x4){0.f, 0.f, 0.f, 0.f};
      acc[f][1] = (f32x4){0.f, 0.f, 0.f, 0.f};
    }
    #pragma unroll
    for (int ks = 0; ks < 8; ++ks) {
      bf16x8 b0 = __builtin_bit_cast(bf16x8, bfr[2 * ks]);
      bf16x8 b1 = __builtin_bit_cast(bf16x8, bfr[2 * ks + 1]);
      const int slot = ((ks * 4 + kq) ^ (l15 & 7)) * 16;
      #pragma unroll
      for (int f = 0; f < 6; ++f) {
        const int lr = (f >> 1) * 32 + (f & 1) * 16 + l15;
        bf16x8 a = ldb8((const char*)Wl + lr * 512 + slot);
        acc[f][0] = __builtin_amdgcn_mfma_f32_16x16x32_bf16(a, b0, acc[f][0], 0, 0, 0);
        acc[f][1] = __builtin_amdgcn_mfma_f32_16x16x32_bf16(a, b1, acc[f][1], 0, 0, 0);
      }
    }
    if (im == 0) {
      const u16* xTb2 = xT + (size_t)(bb0 + 1) * HW * 256;
      #pragma unroll
      for (int ks = 0; ks < 8; ++ks) {
        bfr[2 * ks]     = *(const uint4*)(xTb2 + (size_t)(wv * 32      + l15) * 256 + ks * 32 + kq * 8);
        bfr[2 * ks + 1] = *(const uint4*)(xTb2 + (size_t)(wv * 32 + 16 + l15) * 256 + ks * 32 + kq * 8);
      }
    }
    #pragma unroll
    for (int f = 0; f < 6; ++f) {
      const int ch0 = f * 16 + kq * 4;
      const float s0 = stl[ch0],     t0 = stl[96 + ch0];
      const float s1 = stl[ch0 + 1], t1 = stl[96 + ch0 + 1];
      const float s2 = stl[ch0 + 2], t2 = stl[96 + ch0 + 2];
      const float s3 = stl[ch0 + 3], t3 = stl[96 + ch0 + 3];
      #pragma unroll
      for (int p2 = 0; p2 < 2; ++p2) {
        const int px = wv * 32 + p2 * 16 + l15;
        if (px < HW) {
          const u32 lo = (u32)f2bf(s0 * acc[f][p2][0] + t0)
                       | ((u32)f2bf(s1 * acc[f][p2][1] + t1) << 16);
          const u32 hi = (u32)f2bf(s2 * acc[f][p2][2] + t2)
                       | ((u32)f2bf(s3 * acc[f][p2][3] + t3) << 16);
          *(uint2*)((char*)P + px * 208 + f * 32 + kq * 8) = make_uint2(lo, hi);
        }
      }
    }
    __syncthreads();

    if (tid < HW) {
      const int px = tid;
      const int yy = px / 19, xx = px - yy * 19;
      const bool i0 = yy > 0, i1 = yy < 18, i2 = xx > 0, i3 = xx < 18;
      const int pn0 = i0 ? px - 19 : px, pn1 = i1 ? px + 19 : px;
      const int pn2 = i2 ? px - 1  : px, pn3 = i3 ? px + 1  : px;
      const uint4* Qp = (const uint4*)(Pb + px * 208);
      const uint4 q0 = Qp[0], q1 = Qp[1], q2 = Qp[2], q3 = Qp[3];
      const uint4* K0 = (const uint4*)(Pb + pn0 * 208 + 64);
      const uint4* K1 = (const uint4*)(Pb + pn1 * 208 + 64);
      const uint4* K2 = (const uint4*)(Pb + pn2 * 208 + 64);
      const uint4* K3 = (const uint4*)(Pb + pn3 * 208 + 64);
      float l0 = dot8(q0, K0[0]) + dot8(q1, K0[1]) + dot8(q2, K0[2]) + dot8(q3, K0[3]);
      float l1 = dot8(q0, K1[0]) + dot8(q1, K1[1]) + dot8(q2, K1[2]) + dot8(q3, K1[3]);
      float l2 = dot8(q0, K2[0]) + dot8(q1, K2[1]) + dot8(q2, K2[2]) + dot8(q3, K2[3]);
      float l3 = dot8(q0, K3[0]) + dot8(q1, K3[1]) + dot8(q2, K3[2]) + dot8(q3, K3[3]);
      l0 = i0 ? l0 : 0.f; l1 = i1 ? l1 : 0.f;
      l2 = i2 ? l2 : 0.f; l3 = i3 ? l3 : 0.f;
      const float mx = fmaxf(fmaxf(l0, l1), fmaxf(l2, l3));
      const float e0 = __expf(l0 - mx), e1 = __expf(l1 - mx);
      const float e2 = __expf(l2 - mx), e3 = __expf(l3 - mx);
      const float inv = 1.f / (e0 + e1 + e2 + e3);
      aL[0 * HW + px] = i0 ? e0 * inv : 0.f;
      aL[1 * HW + px] = i1 ? e1 * inv : 0.f;
      aL[2 * HW + px] = i2 ? e2 * inv : 0.f;
      aL[3 * HW + px] = i3 ? e3 * inv : 0.f;
    }
    __syncthreads();

    if (pact) {
      const int px = ppx;
      const size_t pgb = ((size_t)bb * 256 + h * 32 + poc0) * HW + px;
      const int yy = px / 19, xx = px - yy * 19;
      const int pn0 = (yy > 0)  ? px - 19 : px, pn1 = (yy < 18) ? px + 19 : px;
      const int pn2 = (xx > 0)  ? px - 1  : px, pn3 = (xx < 18) ? px + 1  : px;
      const float a0 = aL[0 * HW + px], a1 = aL[1 * HW + px];
      const float a2 = aL[2 * HW + px], a3 = aL[3 * HW + px];
      const int vb = 128 + poc0 * 2;
      const uint4* V0 = (const uint4*)(Pb + pn0 * 208 + vb);
      const uint4* V1 = (const uint4*)(Pb + pn1 * 208 + vb);
      const uint4* V2 = (const uint4*)(Pb + pn2 * 208 + vb);
      const uint4* V3 = (const uint4*)(Pb + pn3 * 208 + vb);
      #pragma unroll
      for (int half = 0; half < 2; ++half) {
        const uint4 w0 = V0[half], w1 = V1[half], w2 = V2[half], w3 = V3[half];
        const u32 u0[4] = {w0.x, w0.y, w0.z, w0.w};
        const u32 u1[4] = {w1.x, w1.y, w1.z, w1.w};
        const u32 u2[4] = {w2.x, w2.y, w2.z, w2.w};
        const u32 u3[4] = {w3.x, w3.y, w3.z, w3.w};
        #pragma unroll
        for (int p = 0; p < 4; ++p) {
          const int o = half * 8 + p * 2;
          float vlo = a0 * bf2f((u16)u0[p]) + a1 * bf2f((u16)u1[p])
                    + a2 * bf2f((u16)u2[p]) + a3 * bf2f((u16)u3[p]);
          float vhi = a0 * bf2f((u16)(u0[p] >> 16)) + a1 * bf2f((u16)(u1[p] >> 16))
                    + a2 * bf2f((u16)(u2[p] >> 16)) + a3 * bf2f((u16)(u3[p] >> 16));
          vlo = fmaxf(vlo, 0.f);
          vhi = fmaxf(vhi, 0.f);
          out[pgb + (size_t)o * HW]       = vlo + xres[o];
          out[pgb + (size_t)(o + 1) * HW] = vhi + xres[o + 1];
        }
      }
    }
    if (im == 0 && pact) {
      const uint4* xr2 = (const uint4*)(xT + ((size_t)(bb0 + 1) * HW + ppx) * 256 + h * 32 + poc0);
      const uint4 r0 = xr2[0], r1 = xr2[1];
      const u32 uu[8] = {r0.x, r0.y, r0.z, r0.w, r1.x, r1.y, r1.z, r1.w};
      #pragma unroll
      for (int p = 0; p < 8; ++p) {
        xres[2 * p]     = bf2f((u16)uu[p]);
        xres[2 * p + 1] = bf2f((u16)(uu[p] >> 16));
      }
    }
    __syncthreads();
  }
}

// ---------------- workspace layout
constexpr size_t OFF_XT    = 0;
constexpr size_t SZ_XT     = (size_t)NPIX * 512 + 16384;
constexpr size_t OFF_WALL  = OFF_XT + SZ_XT;
constexpr size_t SZ_WALL   = (size_t)NTOT * 512;
constexpr size_t OFF_BALL  = OFF_WALL + SZ_WALL;
constexpr size_t OFF_M     = OFF_BALL + NTOT * 4;
constexpr size_t SZ_M      = 256 * 256 * 4;
constexpr size_t OFF_SX    = OFF_M + SZ_M;
constexpr size_t OFF_SALL  = OFF_SX + 256 * 4;
constexpr size_t OFF_TALL  = OFF_SALL + NTOT * 4;
constexpr size_t OFF_MPART = OFF_TALL + NTOT * 4;
constexpr size_t SZ_MPART  = (size_t)256 * 65536 * 4;   // 67 MB
constexpr size_t WS_NEEDED = OFF_MPART + SZ_MPART;

extern "C" void kernel_launch(void* const* d_in, const int* in_sizes, int n_in,
                              void* d_out, int out_size, void* d_ws, size_t ws_size,
                              hipStream_t stream) {
  (void)in_sizes; (void)n_in; (void)out_size;
  if (ws_size < WS_NEEDED) return;

  const float* x     = (const float*)d_in[0];
  const float* Wq    = (const float*)d_in[1];
  const float* bq    = (const float*)d_in[2];
  const float* Wk    = (const float*)d_in[3];
  const float* bk    = (const float*)d_in[4];
  const float* Wv    = (const float*)d_in[5];
  const float* bv    = (const float*)d_in[6];
  const float* gQ    = (const float*)d_in[7];
  const float* betaQ = (const float*)d_in[8];
  const float* gK    = (const float*)d_in[9];
  const float* betaK = (const float*)d_in[10];
  const float* gV    = (const float*)d_in[11];
  const float* betaV = (const float*)d_in[12];
  float* out = (float*)d_out;

  char* wsp = (char*)d_ws;
  u16*   xT    = (u16*)(wsp + OFF_XT);
  u16*   Wall  = (u16*)(wsp + OFF_WALL);
  float* ball  = (float*)(wsp + OFF_BALL);
  float* Mg    = (float*)(wsp + OFF_M);
  float* sx    = (float*)(wsp + OFF_SX);
  float* s_all = (float*)(wsp + OFF_SALL);
  float* t_all = (float*)(wsp + OFF_TALL);
  float* Mpart = (float*)(wsp + OFF_MPART);

  k_prep<<<NTOT, 256, 0, stream>>>(Wq, bq, Wk, bk, Wv, bv, Wall, ball, sx);
  k_M<<<256, 512, 0, stream>>>(x, xT, Mpart, sx);
  k_red<<<256, 256, 0, stream>>>(Mpart, Mg);
  k_stats2<<<NTOT, 256, 0, stream>>>(Mg, sx, Wq, bq, Wk, bk, Wv, bv,
                                     gQ, betaQ, gK, betaK, gV, betaV, s_all, t_all);
  k_fused<<<2048, 768, 0, stream>>>(xT, Wall, ball, s_all, t_all, out);
}

// Round 21
// 363.623 us; speedup vs baseline: 1.1763x; 1.0297x over previous
//
#include <hip/hip_runtime.h>

typedef unsigned short u16;
typedef unsigned int   u32;

#define NB     512
#define NHEADS 8
#define HW     361
#define NPIX   184832      /* NB*HW */
#define NTOT   768
#define EPSBN  1e-5f
#define RS     0.17677669529663687f   /* sqrt(32)/32 */

typedef __bf16 bf16x8 __attribute__((ext_vector_type(8)));
typedef float  f32x4  __attribute__((ext_vector_type(4)));

__device__ __forceinline__ u16 f2bf(float f) {
  u32 u = __float_as_uint(f);
  u += 0x7fffu + ((u >> 16) & 1u);          // round-to-nearest-even
  return (u16)(u >> 16);
}
__device__ __forceinline__ float bf2f(u16 v) {
  return __uint_as_float(((u32)v) << 16);
}
__device__ __forceinline__ bf16x8 ldb8(const void* p) {
  return __builtin_bit_cast(bf16x8, *(const uint4*)p);
}
__device__ __forceinline__ float dot2(u32 a, u32 b) {
  return bf2f((u16)a) * bf2f((u16)b) + bf2f((u16)(a >> 16)) * bf2f((u16)(b >> 16));
}
__device__ __forceinline__ float dot8(uint4 a, uint4 b) {
  return dot2(a.x, b.x) + dot2(a.y, b.y) + dot2(a.z, b.z) + dot2(a.w, b.w);
}

// ---------------- kernel 0: W -> bf16 [768][256]; bias; zero sx
__global__ __launch_bounds__(256) void k_prep(
    const float* __restrict__ Wq, const float* __restrict__ bq,
    const float* __restrict__ Wk, const float* __restrict__ bk,
    const float* __restrict__ Wv, const float* __restrict__ bv,
    u16* __restrict__ Wall, float* __restrict__ ball,
    float* __restrict__ sx) {
  const int n = blockIdx.x, t = threadIdx.x;
  const float* src; const float* bs; int r;
  if (n < 256)      { src = Wq; bs = bq; r = n; }
  else if (n < 512) { src = Wk; bs = bk; r = n - 256; }
  else              { src = Wv; bs = bv; r = n - 512; }
  Wall[n * 256 + t] = f2bf(src[r * 256 + t]);
  if (t == 0) ball[n] = bs[r];
  if (n == 0) sx[t] = 0.f;
}

// ---------------- kernel 1: M partials + sx + fused xT write (x read ONCE)
// R16 version (known-good): 256 blocks (2 images) x 512 thr; acc[2][16]
__global__ __launch_bounds__(512) void k_M(
    const float* __restrict__ x, u16* __restrict__ xT,
    float* __restrict__ Mpart, float* __restrict__ sx) {
  __shared__ u16 Als[256 * 64];                    // 32 KB
  const int tid = threadIdx.x, g = blockIdx.x;     // images 2g, 2g+1
  const int lane = tid & 63, w = tid >> 6;         // 8 waves
  const int l15 = lane & 15, kq = lane >> 4;
  const int sc  = tid >> 4;                        // staging c low (0..31)
  const int sq  = tid & 15;                        // staging px quad
  const int wpx = tid & 63;                        // xT-write px in chunk
  const int wcs = tid >> 6;                        // xT-write c-slice (*32)
  char* Ab = (char*)Als;

  float sxp[8];
  f32x4 acc[2][16];
  #pragma unroll
  for (int i = 0; i < 8; ++i) sxp[i] = 0.f;
  #pragma unroll
  for (int f2 = 0; f2 < 16; ++f2) {
    acc[0][f2] = (f32x4){0.f, 0.f, 0.f, 0.f};
    acc[1][f2] = (f32x4){0.f, 0.f, 0.f, 0.f};
  }

  #pragma unroll 1
  for (int ch = 0; ch < 12; ++ch) {
    const int img = (ch >= 6) ? 1 : 0;
    const int px0 = (ch - img * 6) * 64;
    const int bb  = g * 2 + img;
    const int pb  = px0 + sq * 4;
    #pragma unroll
    for (int i = 0; i < 8; ++i) {
      const int c = sc + 32 * i;
      const float* xp = x + ((size_t)bb * 256 + c) * HW + pb;
      float v0, v1, v2, v3;
      if (pb + 3 < HW) {
        const float4 f4 = *(const float4*)xp;
        v0 = f4.x; v1 = f4.y; v2 = f4.z; v3 = f4.w;
      } else {
        v0 = (pb + 0 < HW) ? xp[0] : 0.f;
        v1 = (pb + 1 < HW) ? xp[1] : 0.f;
        v2 = (pb + 2 < HW) ? xp[2] : 0.f;
        v3 = (pb + 3 < HW) ? xp[3] : 0.f;
      }
      sxp[i] += v0 + v1 + v2 + v3;
      const u32 lo = (u32)f2bf(v0) | ((u32)f2bf(v1) << 16);
      const u32 hi = (u32)f2bf(v2) | ((u32)f2bf(v3) << 16);
      const int slot = (sq >> 1) ^ (c & 7);        // XOR swizzle
      *(uint2*)(Ab + c * 128 + slot * 16 + (sq & 1) * 8) = make_uint2(lo, hi);
    }
    __syncthreads();
    #pragma unroll
    for (int kk = 0; kk < 2; ++kk) {
      const int gl = kk * 4 + kq;
      const int so = ((gl ^ (l15 & 7)) << 4);
      const int r0 = w * 32 + l15;
      const bf16x8 a0 = ldb8(Ab + r0 * 128 + so);
      const bf16x8 a1 = ldb8(Ab + (r0 + 16) * 128 + so);
      #pragma unroll
      for (int f2 = 0; f2 < 16; ++f2) {
        const bf16x8 b = ldb8(Ab + (f2 * 16 + l15) * 128 + so);
        acc[0][f2] = __builtin_amdgcn_mfma_f32_16x16x32_bf16(a0, b, acc[0][f2], 0, 0, 0);
        acc[1][f2] = __builtin_amdgcn_mfma_f32_16x16x32_bf16(a1, b, acc[1][f2], 0, 0, 0);
      }
    }
    const int pxg = px0 + wpx;
    if (pxg < HW) {
      __align__(16) u16 tmp[32];
      #pragma unroll
      for (int j = 0; j < 32; ++j) {
        const int c = wcs * 32 + j;
        tmp[j] = Als[c * 64 + (((wpx >> 3) ^ (c & 7)) << 3) + (wpx & 7)];
      }
      uint4* dst = (uint4*)(xT + ((size_t)bb * HW + pxg) * 256 + wcs * 32);
      dst[0] = ((const uint4*)tmp)[0];
      dst[1] = ((const uint4*)tmp)[1];
      dst[2] = ((const uint4*)tmp)[2];
      dst[3] = ((const uint4*)tmp)[3];
    }
    __syncthreads();
  }
  float* mp = Mpart + (size_t)g * 65536;
  #pragma unroll
  for (int f1 = 0; f1 < 2; ++f1)
    #pragma unroll
    for (int f2 = 0; f2 < 16; ++f2)
      #pragma unroll
      for (int j = 0; j < 4; ++j) {
        const int c1 = w * 32 + f1 * 16 + kq * 4 + j;
        const int c2 = f2 * 16 + l15;
        mp[c1 * 256 + c2] = acc[f1][f2][j];
      }
  #pragma unroll
  for (int i = 0; i < 8; ++i) {
    float v = sxp[i];
    v += __shfl_down(v, 8); v += __shfl_down(v, 4);
    v += __shfl_down(v, 2); v += __shfl_down(v, 1);
    if (sq == 0) atomicAdd(&sx[sc + 32 * i], v);
  }
}

// ---------------- kernel 1c: reduce 256 partials -> Mg (deterministic)
__global__ __launch_bounds__(256) void k_red(const float* __restrict__ Mpart,
                                             float* __restrict__ Mg) {
  const int i = blockIdx.x * 256 + threadIdx.x;
  float s = 0.f;
  #pragma unroll 8
  for (int sl = 0; sl < 256; ++sl) s += Mpart[(size_t)sl * 65536 + i];
  Mg[i] = s;
}

// ---------------- kernel 2: finalize BN via moments: s_all, t_all
__global__ __launch_bounds__(256) void k_stats2(
    const float* __restrict__ Mg, const float* __restrict__ sx,
    const float* __restrict__ Wq, const float* __restrict__ bq,
    const float* __restrict__ Wk, const float* __restrict__ bk,
    const float* __restrict__ Wv, const float* __restrict__ bv,
    const float* __restrict__ gQ, const float* __restrict__ betaQ,
    const float* __restrict__ gK, const float* __restrict__ betaK,
    const float* __restrict__ gV, const float* __restrict__ betaV,
    float* __restrict__ s_all, float* __restrict__ t_all) {
  __shared__ float ws[256];
  __shared__ float r1[4], r2[4];
  const int n = blockIdx.x, i = threadIdx.x;
  const int which = n >> 8, r = n & 255;
  const float* src = (which == 0) ? Wq : (which == 1) ? Wk : Wv;
  const float wi = src[r * 256 + i];
  ws[i] = wi;
  __syncthreads();
  float colsum = 0.f;
  #pragma unroll 4
  for (int j = 0; j < 256; ++j) colsum += Mg[j * 256 + i] * ws[j];
  float p1 = wi * sx[i];
  float p2 = wi * colsum;
  p1 += __shfl_down(p1, 32); p2 += __shfl_down(p2, 32);
  p1 += __shfl_down(p1, 16); p2 += __shfl_down(p2, 16);
  p1 += __shfl_down(p1, 8);  p2 += __shfl_down(p2, 8);
  p1 += __shfl_down(p1, 4);  p2 += __shfl_down(p2, 4);
  p1 += __shfl_down(p1, 2);  p2 += __shfl_down(p2, 2);
  p1 += __shfl_down(p1, 1);  p2 += __shfl_down(p2, 1);
  const int wv = i >> 6;
  if ((i & 63) == 0) { r1[wv] = p1; r2[wv] = p2; }
  __syncthreads();
  if (i == 0) {
    const float S1 = r1[0] + r1[1] + r1[2] + r1[3];
    const float S2 = r2[0] + r2[1] + r2[2] + r2[3];
    const float* bs = (which == 0) ? bq : (which == 1) ? bk : bv;
    const float* gs = (which == 0) ? gQ : (which == 1) ? gK : gV;
    const float* be = (which == 0) ? betaQ : (which == 1) ? betaK : betaV;
    const float b = bs[r];
    const float P = (float)NPIX;
    const float mean = (S1 + P * b) / P;
    const float Ey2  = (S2 + 2.f * b * S1 + P * b * b) / P;
    const float var  = Ey2 - mean * mean;
    const float s    = gs[r] * rsqrtf(var + EPSBN);
    s_all[n] = s;
    t_all[n] = be[r] - s * mean;
  }
}

// ---------------- kernel 3: fused QKV-GEMM + neighbor attention
// 4 images/block (grid 1024); softmax fused into output phase (no aL, 2 barriers/img)
__global__ __launch_bounds__(768) void k_fused(
    const u16* __restrict__ xT, const u16* __restrict__ Wall,
    const float* __restrict__ ball,
    const float* __restrict__ s_all, const float* __restrict__ t_all,
    float* __restrict__ out) {
  __shared__ u16   Wl[96 * 256];                   // 48 KB, XOR-swizzled rows
  __shared__ __align__(16) u16 P[HW * 104];        // 75,088 B: [px][Q|K|V]
  __shared__ float stl[2 * 96];
  const int tid = threadIdx.x;
  const int wg  = blockIdx.x;                      // 0..1023
  const int xcd = wg & 7, ii = wg >> 3;            // ii 0..127
  const int h   = ii & 7;
  const int pr  = xcd * 16 + (ii >> 3);            // image quad 0..127
  const int bb0 = pr * 4;
  const char* Pb = (const char*)P;

  const int lane = tid & 63, wv = tid >> 6;
  const int l15 = lane & 15, kq = lane >> 4;

  const bool pact = tid < 2 * HW;
  const int  ppx  = pact ? ((tid < HW) ? tid : tid - HW) : 0;
  const int  poc0 = (tid < HW) ? 0 : 16;

  uint4 bfr[16];
  {
    const u16* xTb = xT + (size_t)bb0 * HW * 256;
    #pragma unroll
    for (int ks = 0; ks < 8; ++ks) {
      bfr[2 * ks]     = *(const uint4*)(xTb + (size_t)(wv * 32      + l15) * 256 + ks * 32 + kq * 8);
      bfr[2 * ks + 1] = *(const uint4*)(xTb + (size_t)(wv * 32 + 16 + l15) * 256 + ks * 32 + kq * 8);
    }
  }
  // residual prefetch from bf16 xT (channels h*32+poc0 .. +16, contiguous)
  float xres[16];
  if (pact) {
    const uint4* xr = (const uint4*)(xT + ((size_t)bb0 * HW + ppx) * 256 + h * 32 + poc0);
    const uint4 r0 = xr[0], r1 = xr[1];
    const u32 uu[8] = {r0.x, r0.y, r0.z, r0.w, r1.x, r1.y, r1.z, r1.w};
    #pragma unroll
    for (int p = 0; p < 8; ++p) {
      xres[2 * p]     = bf2f((u16)uu[p]);
      xres[2 * p + 1] = bf2f((u16)(uu[p] >> 16));
    }
  }
  if (tid < 96) {
    const int which = tid >> 5, c32 = tid & 31;
    const int n = which * 256 + h * 32 + c32;
    float s = s_all[n];
    float t = s * ball[n] + t_all[n];
    if (tid < 32) { s *= RS; t *= RS; }
    stl[tid] = s; stl[96 + tid] = t;
  }
  #pragma unroll
  for (int i = 0; i < 4; ++i) {
    const int gi = tid + i * 768;
    const int lr = gi >> 5, gg = gi & 31;
    const int which = lr >> 5, c32 = lr & 31;
    uint4 v = *(const uint4*)(Wall + (size_t)(which * 256 + h * 32 + c32) * 256 + gg * 8);
    const int slot = gg ^ (lr & 7);
    *(uint4*)((char*)Wl + lr * 512 + slot * 16) = v;
  }
  __syncthreads();

  #pragma unroll 1
  for (int im = 0; im < 4; ++im) {
    const int bb = bb0 + im;
    f32x4 acc[6][2];
    #pragma unroll
    for (int f = 0; f < 6; ++f) {
      acc[f][0] = (f32x4){0.f, 0.f, 0.f, 0.f};
      acc[f][1] = (f32x4){0.f, 0.f, 0.f, 0.f};
    }
    #pragma unroll
    for (int ks = 0; ks < 8; ++ks) {
      bf16x8 b0 = __builtin_bit_cast(bf16x8, bfr[2 * ks]);
      bf16x8 b1 = __builtin_bit_cast(bf16x8, bfr[2 * ks + 1]);
      const int slot = ((ks * 4 + kq) ^ (l15 & 7)) * 16;
      #pragma unroll
      for (int f = 0; f < 6; ++f) {
        const int lr = (f >> 1) * 32 + (f & 1) * 16 + l15;
        bf16x8 a = ldb8((const char*)Wl + lr * 512 + slot);
        acc[f][0] = __builtin_amdgcn_mfma_f32_16x16x32_bf16(a, b0, acc[f][0], 0, 0, 0);
        acc[f][1] = __builtin_amdgcn_mfma_f32_16x16x32_bf16(a, b1, acc[f][1], 0, 0, 0);
      }
    }
    if (im < 3) {                                  // prefetch next image B-frags
      const u16* xTb2 = xT + (size_t)(bb + 1) * HW * 256;
      #pragma unroll
      for (int ks = 0; ks < 8; ++ks) {
        bfr[2 * ks]     = *(const uint4*)(xTb2 + (size_t)(wv * 32      + l15) * 256 + ks * 32 + kq * 8);
        bfr[2 * ks + 1] = *(const uint4*)(xTb2 + (size_t)(wv * 32 + 16 + l15) * 256 + ks * 32 + kq * 8);
      }
    }
    #pragma unroll
    for (int f = 0; f < 6; ++f) {
      const int ch0 = f * 16 + kq * 4;
      const float s0 = stl[ch0],     t0 = stl[96 + ch0];
      const float s1 = stl[ch0 + 1], t1 = stl[96 + ch0 + 1];
      const float s2 = stl[ch0 + 2], t2 = stl[96 + ch0 + 2];
      const float s3 = stl[ch0 + 3], t3 = stl[96 + ch0 + 3];
      #pragma unroll
      for (int p2 = 0; p2 < 2; ++p2) {
        const int px = wv * 32 + p2 * 16 + l15;
        if (px < HW) {
          const u32 lo = (u32)f2bf(s0 * acc[f][p2][0] + t0)
                       | ((u32)f2bf(s1 * acc[f][p2][1] + t1) << 16);
          const u32 hi = (u32)f2bf(s2 * acc[f][p2][2] + t2)
                       | ((u32)f2bf(s3 * acc[f][p2][3] + t3) << 16);
          *(uint2*)((char*)P + px * 208 + f * 32 + kq * 8) = make_uint2(lo, hi);
        }
      }
    }
    __syncthreads();

    // fused softmax + weighted-V + ReLU + residual (each thread owns (px, oc-half))
    if (pact) {
      const int px = ppx;
      const size_t pgb = ((size_t)bb * 256 + h * 32 + poc0) * HW + px;
      const int yy = px / 19, xx = px - yy * 19;
      const bool i0 = yy > 0, i1 = yy < 18, i2 = xx > 0, i3 = xx < 18;
      const int pn0 = i0 ? px - 19 : px, pn1 = i1 ? px + 19 : px;
      const int pn2 = i2 ? px - 1  : px, pn3 = i3 ? px + 1  : px;
      const uint4* Qp = (const uint4*)(Pb + px * 208);
      const uint4 q0 = Qp[0], q1 = Qp[1], q2 = Qp[2], q3 = Qp[3];
      const uint4* K0 = (const uint4*)(Pb + pn0 * 208 + 64);
      const uint4* K1 = (const uint4*)(Pb + pn1 * 208 + 64);
      const uint4* K2 = (const uint4*)(Pb + pn2 * 208 + 64);
      const uint4* K3 = (const uint4*)(Pb + pn3 * 208 + 64);
      float l0 = dot8(q0, K0[0]) + dot8(q1, K0[1]) + dot8(q2, K0[2]) + dot8(q3, K0[3]);
      float l1 = dot8(q0, K1[0]) + dot8(q1, K1[1]) + dot8(q2, K1[2]) + dot8(q3, K1[3]);
      float l2 = dot8(q0, K2[0]) + dot8(q1, K2[1]) + dot8(q2, K2[2]) + dot8(q3, K2[3]);
      float l3 = dot8(q0, K3[0]) + dot8(q1, K3[1]) + dot8(q2, K3[2]) + dot8(q3, K3[3]);
      l0 = i0 ? l0 : 0.f; l1 = i1 ? l1 : 0.f;
      l2 = i2 ? l2 : 0.f; l3 = i3 ? l3 : 0.f;
      const float mx = fmaxf(fmaxf(l0, l1), fmaxf(l2, l3));
      const float e0 = __expf(l0 - mx), e1 = __expf(l1 - mx);
      const float e2 = __expf(l2 - mx), e3 = __expf(l3 - mx);
      const float inv = 1.f / (e0 + e1 + e2 + e3);
      const float a0 = i0 ? e0 * inv : 0.f;
      const float a1 = i1 ? e1 * inv : 0.f;
      const float a2 = i2 ? e2 * inv : 0.f;
      const float a3 = i3 ? e3 * inv : 0.f;
      const int vb = 128 + poc0 * 2;
      const uint4* V0 = (const uint4*)(Pb + pn0 * 208 + vb);
      const uint4* V1 = (const uint4*)(Pb + pn1 * 208 + vb);
      const uint4* V2 = (const uint4*)(Pb + pn2 * 208 + vb);
      const uint4* V3 = (const uint4*)(Pb + pn3 * 208 + vb);
      #pragma unroll
      for (int half = 0; half < 2; ++half) {
        const uint4 w0 = V0[half], w1 = V1[half], w2 = V2[half], w3 = V3[half];
        const u32 u0[4] = {w0.x, w0.y, w0.z, w0.w};
        const u32 u1[4] = {w1.x, w1.y, w1.z, w1.w};
        const u32 u2[4] = {w2.x, w2.y, w2.z, w2.w};
        const u32 u3[4] = {w3.x, w3.y, w3.z, w3.w};
        #pragma unroll
        for (int p = 0; p < 4; ++p) {
          const int o = half * 8 + p * 2;
          float vlo = a0 * bf2f((u16)u0[p]) + a1 * bf2f((u16)u1[p])
                    + a2 * bf2f((u16)u2[p]) + a3 * bf2f((u16)u3[p]);
          float vhi = a0 * bf2f((u16)(u0[p] >> 16)) + a1 * bf2f((u16)(u1[p] >> 16))
                    + a2 * bf2f((u16)(u2[p] >> 16)) + a3 * bf2f((u16)(u3[p] >> 16));
          vlo = fmaxf(vlo, 0.f);
          vhi = fmaxf(vhi, 0.f);
          out[pgb + (size_t)o * HW]       = vlo + xres[o];
          out[pgb + (size_t)(o + 1) * HW] = vhi + xres[o + 1];
        }
      }
    }
    if (im < 3 && pact) {                          // prefetch next image residual
      const uint4* xr2 = (const uint4*)(xT + ((size_t)(bb + 1) * HW + ppx) * 256 + h * 32 + poc0);
      const uint4 r0 = xr2[0], r1 = xr2[1];
      const u32 uu[8] = {r0.x, r0.y, r0.z, r0.w, r1.x, r1.y, r1.z, r1.w};
      #pragma unroll
      for (int p = 0; p < 8; ++p) {
        xres[2 * p]     = bf2f((u16)uu[p]);
        xres[2 * p + 1] = bf2f((u16)(uu[p] >> 16));
      }
    }
    __syncthreads();
  }
}

// ---------------- workspace layout
constexpr size_t OFF_XT    = 0;
constexpr size_t SZ_XT     = (size_t)NPIX * 512 + 16384;
constexpr size_t OFF_WALL  = OFF_XT + SZ_XT;
constexpr size_t SZ_WALL   = (size_t)NTOT * 512;
constexpr size_t OFF_BALL  = OFF_WALL + SZ_WALL;
constexpr size_t OFF_M     = OFF_BALL + NTOT * 4;
constexpr size_t SZ_M      = 256 * 256 * 4;
constexpr size_t OFF_SX    = OFF_M + SZ_M;
constexpr size_t OFF_SALL  = OFF_SX + 256 * 4;
constexpr size_t OFF_TALL  = OFF_SALL + NTOT * 4;
constexpr size_t OFF_MPART = OFF_TALL + NTOT * 4;
constexpr size_t SZ_MPART  = (size_t)256 * 65536 * 4;   // 67 MB
constexpr size_t WS_NEEDED = OFF_MPART + SZ_MPART;

extern "C" void kernel_launch(void* const* d_in, const int* in_sizes, int n_in,
                              void* d_out, int out_size, void* d_ws, size_t ws_size,
                              hipStream_t stream) {
  (void)in_sizes; (void)n_in; (void)out_size;
  if (ws_size < WS_NEEDED) return;

  const float* x     = (const float*)d_in[0];
  const float* Wq    = (const float*)d_in[1];
  const float* bq    = (const float*)d_in[2];
  const float* Wk    = (const float*)d_in[3];
  const float* bk    = (const float*)d_in[4];
  const float* Wv    = (const float*)d_in[5];
  const float* bv    = (const float*)d_in[6];
  const float* gQ    = (const float*)d_in[7];
  const float* betaQ = (const float*)d_in[8];
  const float* gK    = (const float*)d_in[9];
  const float* betaK = (const float*)d_in[10];
  const float* gV    = (const float*)d_in[11];
  const float* betaV = (const float*)d_in[12];
  float* out = (float*)d_out;

  char* wsp = (char*)d_ws;
  u16*   xT    = (u16*)(wsp + OFF_XT);
  u16*   Wall  = (u16*)(wsp + OFF_WALL);
  float* ball  = (float*)(wsp + OFF_BALL);
  float* Mg    = (float*)(wsp + OFF_M);
  float* sx    = (float*)(wsp + OFF_SX);
  float* s_all = (float*)(wsp + OFF_SALL);
  float* t_all = (float*)(wsp + OFF_TALL);
  float* Mpart = (float*)(wsp + OFF_MPART);

  k_prep<<<NTOT, 256, 0, stream>>>(Wq, bq, Wk, bk, Wv, bv, Wall, ball, sx);
  k_M<<<256, 512, 0, stream>>>(x, xT, Mpart, sx);
  k_red<<<256, 256, 0, stream>>>(Mpart, Mg);
  k_stats2<<<NTOT, 256, 0, stream>>>(Mg, sx, Wq, bq, Wk, bk, Wv, bv,
                                     gQ, betaQ, gK, betaK, gV, betaV, s_all, t_all);
  k_fused<<<1024, 768, 0, stream>>>(xT, Wall, ball, s_all, t_all, out);
}

// Round 22
// 355.642 us; speedup vs baseline: 1.2027x; 1.0224x over previous
//
#include <hip/hip_runtime.h>

typedef unsigned short u16;
typedef unsigned int   u32;

#define NB     512
#define NHEADS 8
#define HW     361
#define NPIX   184832      /* NB*HW */
#define NTOT   768
#define EPSBN  1e-5f
#define RS     0.17677669529663687f   /* sqrt(32)/32 */

typedef __bf16 bf16x8 __attribute__((ext_vector_type(8)));
typedef float  f32x4  __attribute__((ext_vector_type(4)));

__device__ __forceinline__ u16 f2bf(float f) {
  u32 u = __float_as_uint(f);
  u += 0x7fffu + ((u >> 16) & 1u);          // round-to-nearest-even
  return (u16)(u >> 16);
}
__device__ __forceinline__ float bf2f(u16 v) {
  return __uint_as_float(((u32)v) << 16);
}
__device__ __forceinline__ bf16x8 ldb8(const void* p) {
  return __builtin_bit_cast(bf16x8, *(const uint4*)p);
}
__device__ __forceinline__ float dot2(u32 a, u32 b) {
  return bf2f((u16)a) * bf2f((u16)b) + bf2f((u16)(a >> 16)) * bf2f((u16)(b >> 16));
}
__device__ __forceinline__ float dot8(uint4 a, uint4 b) {
  return dot2(a.x, b.x) + dot2(a.y, b.y) + dot2(a.z, b.z) + dot2(a.w, b.w);
}

// ---------------- kernel 0: W -> bf16 [768][256]; bias; zero sx
__global__ __launch_bounds__(256) void k_prep(
    const float* __restrict__ Wq, const float* __restrict__ bq,
    const float* __restrict__ Wk, const float* __restrict__ bk,
    const float* __restrict__ Wv, const float* __restrict__ bv,
    u16* __restrict__ Wall, float* __restrict__ ball,
    float* __restrict__ sx) {
  const int n = blockIdx.x, t = threadIdx.x;
  const float* src; const float* bs; int r;
  if (n < 256)      { src = Wq; bs = bq; r = n; }
  else if (n < 512) { src = Wk; bs = bk; r = n - 256; }
  else              { src = Wv; bs = bv; r = n - 512; }
  Wall[n * 256 + t] = f2bf(src[r * 256 + t]);
  if (t == 0) ball[n] = bs[r];
  if (n == 0) sx[t] = 0.f;
}

// ---------------- kernel 1: M partials + sx + fused xT write (x read ONCE)
// R16 version (known-good): 256 blocks (2 images) x 512 thr; acc[2][16]
__global__ __launch_bounds__(512) void k_M(
    const float* __restrict__ x, u16* __restrict__ xT,
    float* __restrict__ Mpart, float* __restrict__ sx) {
  __shared__ u16 Als[256 * 64];                    // 32 KB
  const int tid = threadIdx.x, g = blockIdx.x;     // images 2g, 2g+1
  const int lane = tid & 63, w = tid >> 6;         // 8 waves
  const int l15 = lane & 15, kq = lane >> 4;
  const int sc  = tid >> 4;                        // staging c low (0..31)
  const int sq  = tid & 15;                        // staging px quad
  const int wpx = tid & 63;                        // xT-write px in chunk
  const int wcs = tid >> 6;                        // xT-write c-slice (*32)
  char* Ab = (char*)Als;

  float sxp[8];
  f32x4 acc[2][16];
  #pragma unroll
  for (int i = 0; i < 8; ++i) sxp[i] = 0.f;
  #pragma unroll
  for (int f2 = 0; f2 < 16; ++f2) {
    acc[0][f2] = (f32x4){0.f, 0.f, 0.f, 0.f};
    acc[1][f2] = (f32x4){0.f, 0.f, 0.f, 0.f};
  }

  #pragma unroll 1
  for (int ch = 0; ch < 12; ++ch) {
    const int img = (ch >= 6) ? 1 : 0;
    const int px0 = (ch - img * 6) * 64;
    const int bb  = g * 2 + img;
    const int pb  = px0 + sq * 4;
    #pragma unroll
    for (int i = 0; i < 8; ++i) {
      const int c = sc + 32 * i;
      const float* xp = x + ((size_t)bb * 256 + c) * HW + pb;
      float v0, v1, v2, v3;
      if (pb + 3 < HW) {
        const float4 f4 = *(const float4*)xp;
        v0 = f4.x; v1 = f4.y; v2 = f4.z; v3 = f4.w;
      } else {
        v0 = (pb + 0 < HW) ? xp[0] : 0.f;
        v1 = (pb + 1 < HW) ? xp[1] : 0.f;
        v2 = (pb + 2 < HW) ? xp[2] : 0.f;
        v3 = (pb + 3 < HW) ? xp[3] : 0.f;
      }
      sxp[i] += v0 + v1 + v2 + v3;
      const u32 lo = (u32)f2bf(v0) | ((u32)f2bf(v1) << 16);
      const u32 hi = (u32)f2bf(v2) | ((u32)f2bf(v3) << 16);
      const int slot = (sq >> 1) ^ (c & 7);        // XOR swizzle
      *(uint2*)(Ab + c * 128 + slot * 16 + (sq & 1) * 8) = make_uint2(lo, hi);
    }
    __syncthreads();
    #pragma unroll
    for (int kk = 0; kk < 2; ++kk) {
      const int gl = kk * 4 + kq;
      const int so = ((gl ^ (l15 & 7)) << 4);
      const int r0 = w * 32 + l15;
      const bf16x8 a0 = ldb8(Ab + r0 * 128 + so);
      const bf16x8 a1 = ldb8(Ab + (r0 + 16) * 128 + so);
      #pragma unroll
      for (int f2 = 0; f2 < 16; ++f2) {
        const bf16x8 b = ldb8(Ab + (f2 * 16 + l15) * 128 + so);
        acc[0][f2] = __builtin_amdgcn_mfma_f32_16x16x32_bf16(a0, b, acc[0][f2], 0, 0, 0);
        acc[1][f2] = __builtin_amdgcn_mfma_f32_16x16x32_bf16(a1, b, acc[1][f2], 0, 0, 0);
      }
    }
    const int pxg = px0 + wpx;
    if (pxg < HW) {
      __align__(16) u16 tmp[32];
      #pragma unroll
      for (int j = 0; j < 32; ++j) {
        const int c = wcs * 32 + j;
        tmp[j] = Als[c * 64 + (((wpx >> 3) ^ (c & 7)) << 3) + (wpx & 7)];
      }
      uint4* dst = (uint4*)(xT + ((size_t)bb * HW + pxg) * 256 + wcs * 32);
      dst[0] = ((const uint4*)tmp)[0];
      dst[1] = ((const uint4*)tmp)[1];
      dst[2] = ((const uint4*)tmp)[2];
      dst[3] = ((const uint4*)tmp)[3];
    }
    __syncthreads();
  }
  float* mp = Mpart + (size_t)g * 65536;
  #pragma unroll
  for (int f1 = 0; f1 < 2; ++f1)
    #pragma unroll
    for (int f2 = 0; f2 < 16; ++f2)
      #pragma unroll
      for (int j = 0; j < 4; ++j) {
        const int c1 = w * 32 + f1 * 16 + kq * 4 + j;
        const int c2 = f2 * 16 + l15;
        mp[c1 * 256 + c2] = acc[f1][f2][j];
      }
  #pragma unroll
  for (int i = 0; i < 8; ++i) {
    float v = sxp[i];
    v += __shfl_down(v, 8); v += __shfl_down(v, 4);
    v += __shfl_down(v, 2); v += __shfl_down(v, 1);
    if (sq == 0) atomicAdd(&sx[sc + 32 * i], v);
  }
}

// ---------------- kernel 1c: reduce 256 partials -> Mg (deterministic)
__global__ __launch_bounds__(256) void k_red(const float* __restrict__ Mpart,
                                             float* __restrict__ Mg) {
  const int i = blockIdx.x * 256 + threadIdx.x;
  float s = 0.f;
  #pragma unroll 8
  for (int sl = 0; sl < 256; ++sl) s += Mpart[(size_t)sl * 65536 + i];
  Mg[i] = s;
}

// ---------------- kernel 2: finalize BN via moments: s_all, t_all
__global__ __launch_bounds__(256) void k_stats2(
    const float* __restrict__ Mg, const float* __restrict__ sx,
    const float* __restrict__ Wq, const float* __restrict__ bq,
    const float* __restrict__ Wk, const float* __restrict__ bk,
    const float* __restrict__ Wv, const float* __restrict__ bv,
    const float* __restrict__ gQ, const float* __restrict__ betaQ,
    const float* __restrict__ gK, const float* __restrict__ betaK,
    const float* __restrict__ gV, const float* __restrict__ betaV,
    float* __restrict__ s_all, float* __restrict__ t_all) {
  __shared__ float ws[256];
  __shared__ float r1[4], r2[4];
  const int n = blockIdx.x, i = threadIdx.x;
  const int which = n >> 8, r = n & 255;
  const float* src = (which == 0) ? Wq : (which == 1) ? Wk : Wv;
  const float wi = src[r * 256 + i];
  ws[i] = wi;
  __syncthreads();
  float colsum = 0.f;
  #pragma unroll 4
  for (int j = 0; j < 256; ++j) colsum += Mg[j * 256 + i] * ws[j];
  float p1 = wi * sx[i];
  float p2 = wi * colsum;
  p1 += __shfl_down(p1, 32); p2 += __shfl_down(p2, 32);
  p1 += __shfl_down(p1, 16); p2 += __shfl_down(p2, 16);
  p1 += __shfl_down(p1, 8);  p2 += __shfl_down(p2, 8);
  p1 += __shfl_down(p1, 4);  p2 += __shfl_down(p2, 4);
  p1 += __shfl_down(p1, 2);  p2 += __shfl_down(p2, 2);
  p1 += __shfl_down(p1, 1);  p2 += __shfl_down(p2, 1);
  const int wv = i >> 6;
  if ((i & 63) == 0) { r1[wv] = p1; r2[wv] = p2; }
  __syncthreads();
  if (i == 0) {
    const float S1 = r1[0] + r1[1] + r1[2] + r1[3];
    const float S2 = r2[0] + r2[1] + r2[2] + r2[3];
    const float* bs = (which == 0) ? bq : (which == 1) ? bk : bv;
    const float* gs = (which == 0) ? gQ : (which == 1) ? gK : gV;
    const float* be = (which == 0) ? betaQ : (which == 1) ? betaK : betaV;
    const float b = bs[r];
    const float P = (float)NPIX;
    const float mean = (S1 + P * b) / P;
    const float Ey2  = (S2 + 2.f * b * S1 + P * b * b) / P;
    const float var  = Ey2 - mean * mean;
    const float s    = gs[r] * rsqrtf(var + EPSBN);
    s_all[n] = s;
    t_all[n] = be[r] - s * mean;
  }
}

// ---------------- kernel 3: fused QKV-GEMM + neighbor attention
// 8 images/block (grid 512); softmax fused into output phase; 2 barriers/img
__global__ __launch_bounds__(768) void k_fused(
    const u16* __restrict__ xT, const u16* __restrict__ Wall,
    const float* __restrict__ ball,
    const float* __restrict__ s_all, const float* __restrict__ t_all,
    float* __restrict__ out) {
  __shared__ u16   Wl[96 * 256];                   // 48 KB, XOR-swizzled rows
  __shared__ __align__(16) u16 P[HW * 104];        // 75,088 B: [px][Q|K|V]
  __shared__ float stl[2 * 96];
  const int tid = threadIdx.x;
  const int wg  = blockIdx.x;                      // 0..511
  const int xcd = wg & 7, ii = wg >> 3;            // ii 0..63
  const int h   = ii & 7;
  const int oc8 = xcd * 8 + (ii >> 3);             // image octet 0..63
  const int bb0 = oc8 * 8;
  const char* Pb = (const char*)P;

  const int lane = tid & 63, wv = tid >> 6;
  const int l15 = lane & 15, kq = lane >> 4;

  const bool pact = tid < 2 * HW;
  const int  ppx  = pact ? ((tid < HW) ? tid : tid - HW) : 0;
  const int  poc0 = (tid < HW) ? 0 : 16;

  uint4 bfr[16];
  {
    const u16* xTb = xT + (size_t)bb0 * HW * 256;
    #pragma unroll
    for (int ks = 0; ks < 8; ++ks) {
      bfr[2 * ks]     = *(const uint4*)(xTb + (size_t)(wv * 32      + l15) * 256 + ks * 32 + kq * 8);
      bfr[2 * ks + 1] = *(const uint4*)(xTb + (size_t)(wv * 32 + 16 + l15) * 256 + ks * 32 + kq * 8);
    }
  }
  // residual prefetch from bf16 xT (channels h*32+poc0 .. +16, contiguous)
  float xres[16];
  if (pact) {
    const uint4* xr = (const uint4*)(xT + ((size_t)bb0 * HW + ppx) * 256 + h * 32 + poc0);
    const uint4 r0 = xr[0], r1 = xr[1];
    const u32 uu[8] = {r0.x, r0.y, r0.z, r0.w, r1.x, r1.y, r1.z, r1.w};
    #pragma unroll
    for (int p = 0; p < 8; ++p) {
      xres[2 * p]     = bf2f((u16)uu[p]);
      xres[2 * p + 1] = bf2f((u16)(uu[p] >> 16));
    }
  }
  if (tid < 96) {
    const int which = tid >> 5, c32 = tid & 31;
    const int n = which * 256 + h * 32 + c32;
    float s = s_all[n];
    float t = s * ball[n] + t_all[n];
    if (tid < 32) { s *= RS; t *= RS; }
    stl[tid] = s; stl[96 + tid] = t;
  }
  #pragma unroll
  for (int i = 0; i < 4; ++i) {
    const int gi = tid + i * 768;
    const int lr = gi >> 5, gg = gi & 31;
    const int which = lr >> 5, c32 = lr & 31;
    uint4 v = *(const uint4*)(Wall + (size_t)(which * 256 + h * 32 + c32) * 256 + gg * 8);
    const int slot = gg ^ (lr & 7);
    *(uint4*)((char*)Wl + lr * 512 + slot * 16) = v;
  }
  __syncthreads();

  #pragma unroll 1
  for (int im = 0; im < 8; ++im) {
    const int bb = bb0 + im;
    f32x4 acc[6][2];
    #pragma unroll
    for (int f = 0; f < 6; ++f) {
      acc[f][0] = (f32x4){0.f, 0.f, 0.f, 0.f};
      acc[f][1] = (f32x4){0.f, 0.f, 0.f, 0.f};
    }
    #pragma unroll
    for (int ks = 0; ks < 8; ++ks) {
      bf16x8 b0 = __builtin_bit_cast(bf16x8, bfr[2 * ks]);
      bf16x8 b1 = __builtin_bit_cast(bf16x8, bfr[2 * ks + 1]);
      const int slot = ((ks * 4 + kq) ^ (l15 & 7)) * 16;
      #pragma unroll
      for (int f = 0; f < 6; ++f) {
        const int lr = (f >> 1) * 32 + (f & 1) * 16 + l15;
        bf16x8 a = ldb8((const char*)Wl + lr * 512 + slot);
        acc[f][0] = __builtin_amdgcn_mfma_f32_16x16x32_bf16(a, b0, acc[f][0], 0, 0, 0);
        acc[f][1] = __builtin_amdgcn_mfma_f32_16x16x32_bf16(a, b1, acc[f][1], 0, 0, 0);
      }
    }
    if (im < 7) {                                  // prefetch next image B-frags
      const u16* xTb2 = xT + (size_t)(bb + 1) * HW * 256;
      #pragma unroll
      for (int ks = 0; ks < 8; ++ks) {
        bfr[2 * ks]     = *(const uint4*)(xTb2 + (size_t)(wv * 32      + l15) * 256 + ks * 32 + kq * 8);
        bfr[2 * ks + 1] = *(const uint4*)(xTb2 + (size_t)(wv * 32 + 16 + l15) * 256 + ks * 32 + kq * 8);
      }
    }
    #pragma unroll
    for (int f = 0; f < 6; ++f) {
      const int ch0 = f * 16 + kq * 4;
      const float s0 = stl[ch0],     t0 = stl[96 + ch0];
      const float s1 = stl[ch0 + 1], t1 = stl[96 + ch0 + 1];
      const float s2 = stl[ch0 + 2], t2 = stl[96 + ch0 + 2];
      const float s3 = stl[ch0 + 3], t3 = stl[96 + ch0 + 3];
      #pragma unroll
      for (int p2 = 0; p2 < 2; ++p2) {
        const int px = wv * 32 + p2 * 16 + l15;
        if (px < HW) {
          const u32 lo = (u32)f2bf(s0 * acc[f][p2][0] + t0)
                       | ((u32)f2bf(s1 * acc[f][p2][1] + t1) << 16);
          const u32 hi = (u32)f2bf(s2 * acc[f][p2][2] + t2)
                       | ((u32)f2bf(s3 * acc[f][p2][3] + t3) << 16);
          *(uint2*)((char*)P + px * 208 + f * 32 + kq * 8) = make_uint2(lo, hi);
        }
      }
    }
    __syncthreads();

    // fused softmax + weighted-V + ReLU + residual (each thread owns (px, oc-half))
    if (pact) {
      const int px = ppx;
      const size_t pgb = ((size_t)bb * 256 + h * 32 + poc0) * HW + px;
      const int yy = px / 19, xx = px - yy * 19;
      const bool i0 = yy > 0, i1 = yy < 18, i2 = xx > 0, i3 = xx < 18;
      const int pn0 = i0 ? px - 19 : px, pn1 = i1 ? px + 19 : px;
      const int pn2 = i2 ? px - 1  : px, pn3 = i3 ? px + 1  : px;
      const uint4* Qp = (const uint4*)(Pb + px * 208);
      const uint4 q0 = Qp[0], q1 = Qp[1], q2 = Qp[2], q3 = Qp[3];
      const uint4* K0 = (const uint4*)(Pb + pn0 * 208 + 64);
      const uint4* K1 = (const uint4*)(Pb + pn1 * 208 + 64);
      const uint4* K2 = (const uint4*)(Pb + pn2 * 208 + 64);
      const uint4* K3 = (const uint4*)(Pb + pn3 * 208 + 64);
      float l0 = dot8(q0, K0[0]) + dot8(q1, K0[1]) + dot8(q2, K0[2]) + dot8(q3, K0[3]);
      float l1 = dot8(q0, K1[0]) + dot8(q1, K1[1]) + dot8(q2, K1[2]) + dot8(q3, K1[3]);
      float l2 = dot8(q0, K2[0]) + dot8(q1, K2[1]) + dot8(q2, K2[2]) + dot8(q3, K2[3]);
      float l3 = dot8(q0, K3[0]) + dot8(q1, K3[1]) + dot8(q2, K3[2]) + dot8(q3, K3[3]);
      l0 = i0 ? l0 : 0.f; l1 = i1 ? l1 : 0.f;
      l2 = i2 ? l2 : 0.f; l3 = i3 ? l3 : 0.f;
      const float mx = fmaxf(fmaxf(l0, l1), fmaxf(l2, l3));
      const float e0 = __expf(l0 - mx), e1 = __expf(l1 - mx);
      const float e2 = __expf(l2 - mx), e3 = __expf(l3 - mx);
      const float inv = 1.f / (e0 + e1 + e2 + e3);
      const float a0 = i0 ? e0 * inv : 0.f;
      const float a1 = i1 ? e1 * inv : 0.f;
      const float a2 = i2 ? e2 * inv : 0.f;
      const float a3 = i3 ? e3 * inv : 0.f;
      const int vb = 128 + poc0 * 2;
      const uint4* V0 = (const uint4*)(Pb + pn0 * 208 + vb);
      const uint4* V1 = (const uint4*)(Pb + pn1 * 208 + vb);
      const uint4* V2 = (const uint4*)(Pb + pn2 * 208 + vb);
      const uint4* V3 = (const uint4*)(Pb + pn3 * 208 + vb);
      #pragma unroll
      for (int half = 0; half < 2; ++half) {
        const uint4 w0 = V0[half], w1 = V1[half], w2 = V2[half], w3 = V3[half];
        const u32 u0[4] = {w0.x, w0.y, w0.z, w0.w};
        const u32 u1[4] = {w1.x, w1.y, w1.z, w1.w};
        const u32 u2[4] = {w2.x, w2.y, w2.z, w2.w};
        const u32 u3[4] = {w3.x, w3.y, w3.z, w3.w};
        #pragma unroll
        for (int p = 0; p < 4; ++p) {
          const int o = half * 8 + p * 2;
          float vlo = a0 * bf2f((u16)u0[p]) + a1 * bf2f((u16)u1[p])
                    + a2 * bf2f((u16)u2[p]) + a3 * bf2f((u16)u3[p]);
          float vhi = a0 * bf2f((u16)(u0[p] >> 16)) + a1 * bf2f((u16)(u1[p] >> 16))
                    + a2 * bf2f((u16)(u2[p] >> 16)) + a3 * bf2f((u16)(u3[p] >> 16));
          vlo = fmaxf(vlo, 0.f);
          vhi = fmaxf(vhi, 0.f);
          out[pgb + (size_t)o * HW]       = vlo + xres[o];
          out[pgb + (size_t)(o + 1) * HW] = vhi + xres[o + 1];
        }
      }
    }
    if (im < 7 && pact) {                          // prefetch next image residual
      const uint4* xr2 = (const uint4*)(xT + ((size_t)(bb + 1) * HW + ppx) * 256 + h * 32 + poc0);
      const uint4 r0 = xr2[0], r1 = xr2[1];
      const u32 uu[8] = {r0.x, r0.y, r0.z, r0.w, r1.x, r1.y, r1.z, r1.w};
      #pragma unroll
      for (int p = 0; p < 8; ++p) {
        xres[2 * p]     = bf2f((u16)uu[p]);
        xres[2 * p + 1] = bf2f((u16)(uu[p] >> 16));
      }
    }
    __syncthreads();
  }
}

// ---------------- workspace layout
constexpr size_t OFF_XT    = 0;
constexpr size_t SZ_XT     = (size_t)NPIX * 512 + 16384;
constexpr size_t OFF_WALL  = OFF_XT + SZ_XT;
constexpr size_t SZ_WALL   = (size_t)NTOT * 512;
constexpr size_t OFF_BALL  = OFF_WALL + SZ_WALL;
constexpr size_t OFF_M     = OFF_BALL + NTOT * 4;
constexpr size_t SZ_M      = 256 * 256 * 4;
constexpr size_t OFF_SX    = OFF_M + SZ_M;
constexpr size_t OFF_SALL  = OFF_SX + 256 * 4;
constexpr size_t OFF_TALL  = OFF_SALL + NTOT * 4;
constexpr size_t OFF_MPART = OFF_TALL + NTOT * 4;
constexpr size_t SZ_MPART  = (size_t)256 * 65536 * 4;   // 67 MB
constexpr size_t WS_NEEDED = OFF_MPART + SZ_MPART;

extern "C" void kernel_launch(void* const* d_in, const int* in_sizes, int n_in,
                              void* d_out, int out_size, void* d_ws, size_t ws_size,
                              hipStream_t stream) {
  (void)in_sizes; (void)n_in; (void)out_size;
  if (ws_size < WS_NEEDED) return;

  const float* x     = (const float*)d_in[0];
  const float* Wq    = (const float*)d_in[1];
  const float* bq    = (const float*)d_in[2];
  const float* Wk    = (const float*)d_in[3];
  const float* bk    = (const float*)d_in[4];
  const float* Wv    = (const float*)d_in[5];
  const float* bv    = (const float*)d_in[6];
  const float* gQ    = (const float*)d_in[7];
  const float* betaQ = (const float*)d_in[8];
  const float* gK    = (const float*)d_in[9];
  const float* betaK = (const float*)d_in[10];
  const float* gV    = (const float*)d_in[11];
  const float* betaV = (const float*)d_in[12];
  float* out = (float*)d_out;

  char* wsp = (char*)d_ws;
  u16*   xT    = (u16*)(wsp + OFF_XT);
  u16*   Wall  = (u16*)(wsp + OFF_WALL);
  float* ball  = (float*)(wsp + OFF_BALL);
  float* Mg    = (float*)(wsp + OFF_M);
  float* sx    = (float*)(wsp + OFF_SX);
  float* s_all = (float*)(wsp + OFF_SALL);
  float* t_all = (float*)(wsp + OFF_TALL);
  float* Mpart = (float*)(wsp + OFF_MPART);

  k_prep<<<NTOT, 256, 0, stream>>>(Wq, bq, Wk, bk, Wv, bv, Wall, ball, sx);
  k_M<<<256, 512, 0, stream>>>(x, xT, Mpart, sx);
  k_red<<<256, 256, 0, stream>>>(Mpart, Mg);
  k_stats2<<<NTOT, 256, 0, stream>>>(Mg, sx, Wq, bq, Wk, bk, Wv, bv,
                                     gQ, betaQ, gK, betaK, gV, betaV, s_all, t_all);
  k_fused<<<512, 768, 0, stream>>>(xT, Wall, ball, s_all, t_all, out);
}